// Round 7
// baseline (763.152 us; speedup 1.0000x reference)
//
#include <hip/hip_runtime.h>

#define NODES 50000
#define NB ((NODES + 255) / 256)   // 196 scan blocks
#define NBUK ((NODES + 63) >> 6)   // 782 dst-buckets of 64 nodes

typedef __attribute__((ext_vector_type(8))) short short8;
typedef __attribute__((ext_vector_type(4))) float f32x4;
typedef __attribute__((ext_vector_type(2))) float f32x2;

__device__ __forceinline__ ushort f2bf(float f) {
    uint u = __float_as_uint(f);
    uint r = (u + 0x7fffu + ((u >> 16) & 1u)) >> 16;
    return (ushort)r;
}
__device__ __forceinline__ float bf2f(ushort u) {
    return __uint_as_float(((uint)u) << 16);
}
// HW OCP-e4m3 on gfx950: encode/decode both via VALU cvt -> self-consistent
__device__ __forceinline__ uchar f2fp8(float f) {
    return (uchar)(__builtin_amdgcn_cvt_pk_fp8_f32(f, f, 0, false) & 0xff);
}

// ---------------- degree / CSR build ----------------

__global__ void k_count(const int* __restrict__ dst, int E, int* __restrict__ degcnt) {
    int e = blockIdx.x * blockDim.x + threadIdx.x;
    if (e < E) atomicAdd(&degcnt[dst[e]], 1);
}

__global__ void k_bsum(const int* __restrict__ cnt, int* __restrict__ bsum) {
    __shared__ int s[256];
    int t = threadIdx.x;
    int i = blockIdx.x * 256 + t;
    s[t] = (i < NODES) ? cnt[i] : 0;
    __syncthreads();
    for (int off = 128; off; off >>= 1) {
        if (t < off) s[t] += s[t + off];
        __syncthreads();
    }
    if (t == 0) bsum[blockIdx.x] = s[0];
}

__global__ void k_bscan(const int* __restrict__ bsum, int* __restrict__ boff, int nb) {
    __shared__ int s[256];
    int t = threadIdx.x;
    s[t] = (t < nb) ? bsum[t] : 0;
    __syncthreads();
    for (int off = 1; off < 256; off <<= 1) {
        int v = (t >= off) ? s[t - off] : 0;
        __syncthreads();
        s[t] += v;
        __syncthreads();
    }
    if (t < nb) boff[t] = (t == 0) ? 0 : s[t - 1];
}

__global__ void k_scan3(const int* __restrict__ cnt, const int* __restrict__ boff,
                        int* __restrict__ rowstart, float* __restrict__ dinv) {
    __shared__ int s[256];
    int t = threadIdx.x;
    int i = blockIdx.x * 256 + t;
    int v = (i < NODES) ? cnt[i] : 0;
    s[t] = v;
    __syncthreads();
    for (int off = 1; off < 256; off <<= 1) {
        int u = (t >= off) ? s[t - off] : 0;
        __syncthreads();
        s[t] += u;
        __syncthreads();
    }
    if (i < NODES) {
        int excl = (t == 0) ? 0 : s[t - 1];
        rowstart[i] = boff[blockIdx.x] + excl;
        dinv[i] = rsqrtf(1.0f + (float)v);
        if (i == NODES - 1) rowstart[NODES] = boff[blockIdx.x] + s[t];
    }
}

// ---------------- two-phase bucketed edge scatter ----------------
// phase B: scatter (src,dst) into dst-bucket regions (dense ~16KB windows)
__global__ void k_bucket(const int* __restrict__ src, const int* __restrict__ dst, int E,
                         const int* __restrict__ rowstart, int* __restrict__ bcur,
                         int2* __restrict__ tmp) {
    int e = blockIdx.x * blockDim.x + threadIdx.x;
    if (e < E) {
        int d = dst[e];
        int b = d >> 6;
        int p = atomicAdd(&bcur[b], 1);
        tmp[rowstart[b << 6] + p] = make_int2(src[e], d);
    }
}

// phase C: within-bucket final CSR placement; writes stay in the bucket window
__global__ void k_final(const int2* __restrict__ tmp, int E,
                        const int* __restrict__ rowstart, int* __restrict__ cursor,
                        const float* __restrict__ dinv, int2* __restrict__ erec) {
    int e = blockIdx.x * blockDim.x + threadIdx.x;
    if (e < E) {
        int2 q = tmp[e];
        int p = atomicAdd(&cursor[q.y], 1);
        erec[rowstart[q.y] + p] = make_int2(q.x, __float_as_int(dinv[q.x]));
    }
}

// ---------------- casts ----------------

__global__ void k_castT(const float* __restrict__ in, ushort* __restrict__ out, int R, int C) {
    int i = blockIdx.x * blockDim.x + threadIdx.x;
    if (i >= R * C) return;
    int r = i / C, c = i % C;
    out[(size_t)c * R + r] = f2bf(in[i]);
}

// ---------------- barrier-free direct MFMA GEMM ----------------
// C[M,N_] = A[M,K] @ Bt[N_,K]^T. BM=64, 4 waves (WM x WN). No LDS, no barriers:
// A-frags read from global (f32->bf16 inline), B-frags from global (L1-resident).
// OUTMODE: 1 = bf16, 2 = fp8-e4m3
template <int N_, int WM, int WN, bool A_F32, int OUTMODE>
__global__ __launch_bounds__(256) void k_gemm_direct(const float* __restrict__ Af,
                                                     const ushort* __restrict__ Ab,
                                                     const ushort* __restrict__ Bt,
                                                     ushort* __restrict__ Cb,
                                                     uchar* __restrict__ C8,
                                                     int M, int K) {
    constexpr int WTM = 64 / WM;
    constexpr int MT = WTM / 16;
    constexpr int WTN = N_ / WN;
    constexpr int NT = WTN / 16;
    int t = threadIdx.x;
    int w = t >> 6, l = t & 63;
    int wm = w % WM, wn = w / WM;
    int bm = blockIdx.x * 64;
    int lr = l & 15, lk = (l >> 4) * 8;

    f32x4 acc[MT][NT] = {};

    for (int k0 = 0; k0 < K; k0 += 32) {
        short8 af[MT];
#pragma unroll
        for (int mt = 0; mt < MT; ++mt) {
            int row = bm + wm * WTM + mt * 16 + lr;
            if (A_F32) {
                ushort r[8] = {0, 0, 0, 0, 0, 0, 0, 0};
                if (row < M) {
                    const float* p = Af + (size_t)row * K + k0 + lk;
                    float4 a = *(const float4*)p;
                    float4 b = *(const float4*)(p + 4);
                    r[0] = f2bf(a.x); r[1] = f2bf(a.y); r[2] = f2bf(a.z); r[3] = f2bf(a.w);
                    r[4] = f2bf(b.x); r[5] = f2bf(b.y); r[6] = f2bf(b.z); r[7] = f2bf(b.w);
                }
                af[mt] = *(short8*)r;
            } else {
                short8 v = {};
                if (row < M) v = *(const short8*)(Ab + (size_t)row * K + k0 + lk);
                af[mt] = v;
            }
        }
        short8 bfr[NT];
#pragma unroll
        for (int nt = 0; nt < NT; ++nt)
            bfr[nt] = *(const short8*)(Bt + (size_t)(wn * WTN + nt * 16 + lr) * K + k0 + lk);
#pragma unroll
        for (int nt = 0; nt < NT; ++nt)
#pragma unroll
            for (int mt = 0; mt < MT; ++mt)
                acc[mt][nt] = __builtin_amdgcn_mfma_f32_16x16x32_bf16(af[mt], bfr[nt], acc[mt][nt], 0, 0, 0);
    }

#pragma unroll
    for (int mt = 0; mt < MT; ++mt)
#pragma unroll
        for (int nt = 0; nt < NT; ++nt)
#pragma unroll
            for (int i = 0; i < 4; ++i) {
                int row = bm + wm * WTM + mt * 16 + (l >> 4) * 4 + i;
                int col = wn * WTN + nt * 16 + lr;
                if (row < M) {
                    float v = acc[mt][nt][i];
                    if (OUTMODE == 1) Cb[(size_t)row * N_ + col] = f2bf(v);
                    else              C8[(size_t)row * N_ + col] = f2fp8(v);
                }
            }
}

// ---------------- layer-1 aggregation + bias + relu (fp8 in / bf16 out) ----------------
__global__ __launch_bounds__(256) void k_agg1(const uchar* __restrict__ h8,
                                              const int* __restrict__ rowstart,
                                              const int2* __restrict__ er,
                                              const float* __restrict__ dinv,
                                              const float* __restrict__ b1,
                                              ushort* __restrict__ out) {
    int wave = threadIdx.x >> 6;
    int lane = threadIdx.x & 63;
    int n = blockIdx.x * 4 + wave;
    if (n >= NODES) return;
    float4 acc = make_float4(0.f, 0.f, 0.f, 0.f);
    int e0 = rowstart[n], e1 = rowstart[n + 1];
    int e = e0;
#define A1_STEP(q, qv)                                                        \
    {                                                                         \
        float w = __int_as_float((q).y);                                      \
        f32x2 lo = __builtin_amdgcn_cvt_pk_f32_fp8((int)(qv), false);         \
        f32x2 hi = __builtin_amdgcn_cvt_pk_f32_fp8((int)(qv), true);          \
        acc.x = fmaf(w, lo[0], acc.x);                                        \
        acc.y = fmaf(w, lo[1], acc.y);                                        \
        acc.z = fmaf(w, hi[0], acc.z);                                        \
        acc.w = fmaf(w, hi[1], acc.w);                                        \
    }
    for (; e + 8 <= e1; e += 8) {
        int2 q0 = er[e],     q1 = er[e + 1], q2 = er[e + 2], q3 = er[e + 3];
        int2 q4 = er[e + 4], q5 = er[e + 5], q6 = er[e + 6], q7 = er[e + 7];
        uint v0 = *(const uint*)(h8 + (size_t)q0.x * 256 + lane * 4);
        uint v1 = *(const uint*)(h8 + (size_t)q1.x * 256 + lane * 4);
        uint v2 = *(const uint*)(h8 + (size_t)q2.x * 256 + lane * 4);
        uint v3 = *(const uint*)(h8 + (size_t)q3.x * 256 + lane * 4);
        uint v4 = *(const uint*)(h8 + (size_t)q4.x * 256 + lane * 4);
        uint v5 = *(const uint*)(h8 + (size_t)q5.x * 256 + lane * 4);
        uint v6 = *(const uint*)(h8 + (size_t)q6.x * 256 + lane * 4);
        uint v7 = *(const uint*)(h8 + (size_t)q7.x * 256 + lane * 4);
        A1_STEP(q0, v0) A1_STEP(q1, v1) A1_STEP(q2, v2) A1_STEP(q3, v3)
        A1_STEP(q4, v4) A1_STEP(q5, v5) A1_STEP(q6, v6) A1_STEP(q7, v7)
    }
    for (; e < e1; ++e) {
        int2 q = er[e];
        uint v = *(const uint*)(h8 + (size_t)q.x * 256 + lane * 4);
        A1_STEP(q, v)
    }
#undef A1_STEP
    float dn = dinv[n];
    float s2 = dn * dn;
    uint qs = *(const uint*)(h8 + (size_t)n * 256 + lane * 4);
    f32x2 slo = __builtin_amdgcn_cvt_pk_f32_fp8((int)qs, false);
    f32x2 shi = __builtin_amdgcn_cvt_pk_f32_fp8((int)qs, true);
    float4 bb = *(const float4*)(b1 + lane * 4);
    ushort4 r;
    r.x = f2bf(fmaxf(fmaf(acc.x, dn, fmaf(slo[0], s2, bb.x)), 0.f));
    r.y = f2bf(fmaxf(fmaf(acc.y, dn, fmaf(slo[1], s2, bb.y)), 0.f));
    r.z = f2bf(fmaxf(fmaf(acc.z, dn, fmaf(shi[0], s2, bb.z)), 0.f));
    r.w = f2bf(fmaxf(fmaf(acc.w, dn, fmaf(shi[1], s2, bb.w)), 0.f));
    *(ushort4*)(out + (size_t)n * 256 + lane * 4) = r;
}

// ---------------- layer-2 aggregation + bias + log_softmax (bf16 h2) ----------------
__global__ __launch_bounds__(256) void k_agg2(const ushort* __restrict__ h,
                                              const int* __restrict__ rowstart,
                                              const int2* __restrict__ er,
                                              const float* __restrict__ dinv,
                                              const float* __restrict__ b2,
                                              float* __restrict__ out) {
    int wave = threadIdx.x >> 6;
    int lane = threadIdx.x & 63;
    int n = blockIdx.x * 4 + wave;
    if (n >= NODES) return;
    float acc = 0.f;
    int e0 = rowstart[n], e1 = rowstart[n + 1];
    int e = e0;
    for (; e + 8 <= e1; e += 8) {
        int2 q0 = er[e],     q1 = er[e + 1], q2 = er[e + 2], q3 = er[e + 3];
        int2 q4 = er[e + 4], q5 = er[e + 5], q6 = er[e + 6], q7 = er[e + 7];
        ushort v0 = h[(size_t)q0.x * 64 + lane];
        ushort v1 = h[(size_t)q1.x * 64 + lane];
        ushort v2 = h[(size_t)q2.x * 64 + lane];
        ushort v3 = h[(size_t)q3.x * 64 + lane];
        ushort v4 = h[(size_t)q4.x * 64 + lane];
        ushort v5 = h[(size_t)q5.x * 64 + lane];
        ushort v6 = h[(size_t)q6.x * 64 + lane];
        ushort v7 = h[(size_t)q7.x * 64 + lane];
        acc = fmaf(__int_as_float(q0.y), bf2f(v0), acc);
        acc = fmaf(__int_as_float(q1.y), bf2f(v1), acc);
        acc = fmaf(__int_as_float(q2.y), bf2f(v2), acc);
        acc = fmaf(__int_as_float(q3.y), bf2f(v3), acc);
        acc = fmaf(__int_as_float(q4.y), bf2f(v4), acc);
        acc = fmaf(__int_as_float(q5.y), bf2f(v5), acc);
        acc = fmaf(__int_as_float(q6.y), bf2f(v6), acc);
        acc = fmaf(__int_as_float(q7.y), bf2f(v7), acc);
    }
    for (; e < e1; ++e) {
        int2 q = er[e];
        acc = fmaf(__int_as_float(q.y), bf2f(h[(size_t)q.x * 64 + lane]), acc);
    }
    float dn = dinv[n];
    float r = fmaf(acc, dn, fmaf(bf2f(h[(size_t)n * 64 + lane]), dn * dn, b2[lane]));
    float m = r;
#pragma unroll
    for (int off = 32; off; off >>= 1) m = fmaxf(m, __shfl_xor(m, off));
    float ex = __expf(r - m);
    float ssum = ex;
#pragma unroll
    for (int off = 32; off; off >>= 1) ssum += __shfl_xor(ssum, off);
    out[(size_t)n * 64 + lane] = r - m - __logf(ssum);
}

// ---------------- launch ----------------

extern "C" void kernel_launch(void* const* d_in, const int* in_sizes, int n_in,
                              void* d_out, int out_size, void* d_ws, size_t ws_size,
                              hipStream_t stream) {
    const float* x  = (const float*)d_in[0];
    const float* W1 = (const float*)d_in[1];
    const float* b1 = (const float*)d_in[2];
    const float* W2 = (const float*)d_in[3];
    const float* b2 = (const float*)d_in[4];
    const int*   ei = (const int*)d_in[5];
    int E = in_sizes[5] / 2;
    const int* src = ei;
    const int* dst = ei + E;
    float* out = (float*)d_out;

    char* wsp = (char*)d_ws;
    auto alloc = [&](size_t bytes) {
        char* p = wsp;
        wsp += (bytes + 255) & ~(size_t)255;
        return p;
    };
    int*    degcnt   = (int*)alloc((size_t)NODES * 4);
    float*  dinv     = (float*)alloc((size_t)NODES * 4);
    int*    rowstart = (int*)alloc((size_t)(NODES + 1) * 4);
    int*    cursor   = (int*)alloc((size_t)NODES * 4);
    int*    bcur     = (int*)alloc((size_t)NBUK * 4);
    int*    bsum     = (int*)alloc((size_t)NB * 4);
    int*    boff     = (int*)alloc((size_t)NB * 4);
    int2*   erec     = (int2*)alloc((size_t)E * 8);
    ushort* w1t      = (ushort*)alloc((size_t)256 * 512 * 2);   // W1^T bf16 [256][512]
    ushort* w2t      = (ushort*)alloc((size_t)64 * 256 * 2);    // W2^T bf16 [64][256]
    uchar*  h1f8     = (uchar*)alloc((size_t)NODES * 256);      // fp8 h1 (12.8 MB)
    ushort* h1ab     = (ushort*)alloc((size_t)NODES * 256 * 2); // bf16 relu(agg1)
    ushort* h2b      = (ushort*)alloc((size_t)NODES * 64 * 2);  // bf16 h2
    int2*   tmp      = (int2*)h1ab;  // bucket staging; dead before h1ab written

    hipMemsetAsync(degcnt, 0, (size_t)NODES * 4, stream);
    hipMemsetAsync(cursor, 0, (size_t)NODES * 4, stream);
    hipMemsetAsync(bcur, 0, (size_t)NBUK * 4, stream);

    k_count<<<(E + 255) / 256, 256, 0, stream>>>(dst, E, degcnt);
    k_bsum<<<NB, 256, 0, stream>>>(degcnt, bsum);
    k_bscan<<<1, 256, 0, stream>>>(bsum, boff, NB);
    k_scan3<<<NB, 256, 0, stream>>>(degcnt, boff, rowstart, dinv);
    k_bucket<<<(E + 255) / 256, 256, 0, stream>>>(src, dst, E, rowstart, bcur, tmp);
    k_final<<<(E + 255) / 256, 256, 0, stream>>>(tmp, E, rowstart, cursor, dinv, erec);

    // weight casts (tiny)
    k_castT<<<(512 * 256 + 255) / 256, 256, 0, stream>>>(W1, w1t, 512, 256);
    k_castT<<<(256 * 64 + 255) / 256, 256, 0, stream>>>(W2, w2t, 256, 64);

    // layer 1: h1 = x @ W1 -> fp8 e4m3 (x read once; barrier-free)
    k_gemm_direct<256, 2, 2, true, 2><<<(NODES + 63) / 64, 256, 0, stream>>>(
        x, nullptr, w1t, nullptr, h1f8, NODES, 512);
    k_agg1<<<(NODES + 3) / 4, 256, 0, stream>>>(h1f8, rowstart, erec, dinv, b1, h1ab);

    // layer 2: h2 = h1a @ W2 -> bf16 (barrier-free)
    k_gemm_direct<64, 4, 1, false, 1><<<(NODES + 63) / 64, 256, 0, stream>>>(
        nullptr, h1ab, w2t, h2b, nullptr, NODES, 256);
    k_agg2<<<(NODES + 3) / 4, 256, 0, stream>>>(h2b, rowstart, erec, dinv, b2, out);
}

// Round 8
// 360.267 us; speedup vs baseline: 2.1183x; 2.1183x over previous
//
#include <hip/hip_runtime.h>

#define NODES 50000
#define NB ((NODES + 255) / 256)   // 196 scan blocks

typedef __attribute__((ext_vector_type(8))) short short8;
typedef __attribute__((ext_vector_type(4))) float f32x4;
typedef __attribute__((ext_vector_type(2))) float f32x2;

__device__ __forceinline__ ushort f2bf(float f) {
    uint u = __float_as_uint(f);
    uint r = (u + 0x7fffu + ((u >> 16) & 1u)) >> 16;
    return (ushort)r;
}
__device__ __forceinline__ float bf2f(ushort u) {
    return __uint_as_float(((uint)u) << 16);
}
// HW OCP-e4m3 on gfx950: encode/decode both via VALU cvt -> self-consistent
__device__ __forceinline__ uchar f2fp8(float f) {
    return (uchar)(__builtin_amdgcn_cvt_pk_fp8_f32(f, f, 0, false) & 0xff);
}

// ---------------- degree / CSR build ----------------

__global__ void k_count(const int* __restrict__ dst, int E, int* __restrict__ degcnt) {
    int e = blockIdx.x * blockDim.x + threadIdx.x;
    if (e < E) atomicAdd(&degcnt[dst[e]], 1);
}

__global__ void k_bsum(const int* __restrict__ cnt, int* __restrict__ bsum) {
    __shared__ int s[256];
    int t = threadIdx.x;
    int i = blockIdx.x * 256 + t;
    s[t] = (i < NODES) ? cnt[i] : 0;
    __syncthreads();
    for (int off = 128; off; off >>= 1) {
        if (t < off) s[t] += s[t + off];
        __syncthreads();
    }
    if (t == 0) bsum[blockIdx.x] = s[0];
}

__global__ void k_bscan(const int* __restrict__ bsum, int* __restrict__ boff, int nb) {
    __shared__ int s[256];
    int t = threadIdx.x;
    s[t] = (t < nb) ? bsum[t] : 0;
    __syncthreads();
    for (int off = 1; off < 256; off <<= 1) {
        int v = (t >= off) ? s[t - off] : 0;
        __syncthreads();
        s[t] += v;
        __syncthreads();
    }
    if (t < nb) boff[t] = (t == 0) ? 0 : s[t - 1];
}

__global__ void k_scan3(const int* __restrict__ cnt, const int* __restrict__ boff,
                        int* __restrict__ rowstart, float* __restrict__ dinv) {
    __shared__ int s[256];
    int t = threadIdx.x;
    int i = blockIdx.x * 256 + t;
    int v = (i < NODES) ? cnt[i] : 0;
    s[t] = v;
    __syncthreads();
    for (int off = 1; off < 256; off <<= 1) {
        int u = (t >= off) ? s[t - off] : 0;
        __syncthreads();
        s[t] += u;
        __syncthreads();
    }
    if (i < NODES) {
        int excl = (t == 0) ? 0 : s[t - 1];
        rowstart[i] = boff[blockIdx.x] + excl;
        dinv[i] = rsqrtf(1.0f + (float)v);
        if (i == NODES - 1) rowstart[NODES] = boff[blockIdx.x] + s[t];
    }
}

// ---------------- casts ----------------

__global__ void k_castT(const float* __restrict__ in, ushort* __restrict__ out, int R, int C) {
    int i = blockIdx.x * blockDim.x + threadIdx.x;
    if (i >= R * C) return;
    int r = i / C, c = i % C;
    out[(size_t)c * R + r] = f2bf(in[i]);
}

// ---------------- fused: GEMM1 (x@W1 -> fp8 h1) ∥ edge scatter ----------------
// blocks [0, gemmBlocks): LDS-tiled MFMA GEMM, BM=64, BN=256, 4 waves (WN=4).
// blocks [gemmBlocks, ...): scatter 2048 edges each into CSR (per-node cursor).
// SA=40 (80B stride): ds_read_b128 rows r / r+8 share banks -> 2-way = free.
__global__ __launch_bounds__(256) void k_gemm1_scatter(
    const float* __restrict__ x, const ushort* __restrict__ w1t,
    uchar* __restrict__ h1f8, int M, int K,
    const int* __restrict__ src, const int* __restrict__ dst, int E,
    const int* __restrict__ rowstart, int* __restrict__ cursor,
    const float* __restrict__ dinv, int2* __restrict__ erec, int gemmBlocks) {
    constexpr int BM = 64, BN = 256;
    constexpr int WTM = 64, MT = 4;   // WM=1
    constexpr int WTN = 64, NT = 4;   // WN=4
    constexpr int SA = 40;
    __shared__ ushort As[BM * SA];
    __shared__ ushort Bs[BN * SA];

    if (blockIdx.x >= gemmBlocks) {
        // ---- scatter path ----
        int base = (blockIdx.x - gemmBlocks) * 2048 + threadIdx.x;
#pragma unroll
        for (int i = 0; i < 8; ++i) {
            int e = base + i * 256;
            if (e < E) {
                int d = dst[e];
                int s = src[e];
                int p = atomicAdd(&cursor[d], 1);
                erec[rowstart[d] + p] = make_int2(s, __float_as_int(dinv[s]));
            }
        }
        return;
    }

    // ---- GEMM path ----
    int t = threadIdx.x;
    int w = t >> 6, l = t & 63;
    int bm = blockIdx.x * BM;
    int lr = l & 15, lk = (l >> 4) * 8;

    f32x4 acc[MT][NT] = {};
    const int ACH = BM * 4;
    const int BCH = BN * 4;

    for (int k0 = 0; k0 < K; k0 += 32) {
        for (int c = t; c < ACH + BCH; c += 256) {
            if (c < ACH) {
                int row = c >> 2, seg = c & 3;
                int gr = bm + row;
                ushort r[8] = {0, 0, 0, 0, 0, 0, 0, 0};
                if (gr < M) {
                    const float* p = x + (size_t)gr * K + k0 + seg * 8;
                    float4 a = *(const float4*)p;
                    float4 b = *(const float4*)(p + 4);
                    r[0] = f2bf(a.x); r[1] = f2bf(a.y); r[2] = f2bf(a.z); r[3] = f2bf(a.w);
                    r[4] = f2bf(b.x); r[5] = f2bf(b.y); r[6] = f2bf(b.z); r[7] = f2bf(b.w);
                }
                *(int4*)(&As[row * SA + seg * 8]) = *(int4*)r;
            } else {
                int cc = c - ACH;
                int row = cc >> 2, seg = cc & 3;
                int4 v = *(const int4*)(w1t + (size_t)row * K + k0 + seg * 8);
                *(int4*)(&Bs[row * SA + seg * 8]) = v;
            }
        }
        __syncthreads();
        short8 af[MT], bfr[NT];
#pragma unroll
        for (int mt = 0; mt < MT; ++mt)
            af[mt] = *(const short8*)(&As[(mt * 16 + lr) * SA + lk]);
#pragma unroll
        for (int nt = 0; nt < NT; ++nt)
            bfr[nt] = *(const short8*)(&Bs[(w * WTN + nt * 16 + lr) * SA + lk]);
#pragma unroll
        for (int mt = 0; mt < MT; ++mt)
#pragma unroll
            for (int nt = 0; nt < NT; ++nt)
                acc[mt][nt] = __builtin_amdgcn_mfma_f32_16x16x32_bf16(af[mt], bfr[nt], acc[mt][nt], 0, 0, 0);
        __syncthreads();
    }

#pragma unroll
    for (int mt = 0; mt < MT; ++mt)
#pragma unroll
        for (int nt = 0; nt < NT; ++nt)
#pragma unroll
            for (int i = 0; i < 4; ++i) {
                int row = bm + mt * 16 + (l >> 4) * 4 + i;
                int col = w * WTN + nt * 16 + lr;
                if (row < M) h1f8[(size_t)row * BN + col] = f2fp8(acc[mt][nt][i]);
            }
}

// ---------------- LDS-tiled MFMA GEMM (layer 2): bf16 in -> bf16 out ----------------
// BM=64, BN=64, WM=4 (wave owns 16 rows x 64 cols), SA=40.
__global__ __launch_bounds__(256) void k_gemm2(const ushort* __restrict__ A,
                                               const ushort* __restrict__ Bt,
                                               ushort* __restrict__ Cb,
                                               int M, int K) {
    constexpr int BM = 64, BN = 64;
    constexpr int WTM = 16, MT = 1;   // WM=4
    constexpr int WTN = 64, NT = 4;   // WN=1
    constexpr int SA = 40;
    __shared__ ushort As[BM * SA];
    __shared__ ushort Bs[BN * SA];

    int t = threadIdx.x;
    int w = t >> 6, l = t & 63;
    int bm = blockIdx.x * BM;
    int lr = l & 15, lk = (l >> 4) * 8;

    f32x4 acc[MT][NT] = {};
    const int ACH = BM * 4;
    const int BCH = BN * 4;

    for (int k0 = 0; k0 < K; k0 += 32) {
        for (int c = t; c < ACH + BCH; c += 256) {
            if (c < ACH) {
                int row = c >> 2, seg = c & 3;
                int gr = bm + row;
                int4 v = make_int4(0, 0, 0, 0);
                if (gr < M) v = *(const int4*)(A + (size_t)gr * K + k0 + seg * 8);
                *(int4*)(&As[row * SA + seg * 8]) = v;
            } else {
                int cc = c - ACH;
                int row = cc >> 2, seg = cc & 3;
                int4 v = *(const int4*)(Bt + (size_t)row * K + k0 + seg * 8);
                *(int4*)(&Bs[row * SA + seg * 8]) = v;
            }
        }
        __syncthreads();
        short8 af, bfr[NT];
        af = *(const short8*)(&As[(w * WTM + lr) * SA + lk]);
#pragma unroll
        for (int nt = 0; nt < NT; ++nt)
            bfr[nt] = *(const short8*)(&Bs[(nt * 16 + lr) * SA + lk]);
#pragma unroll
        for (int nt = 0; nt < NT; ++nt)
            acc[0][nt] = __builtin_amdgcn_mfma_f32_16x16x32_bf16(af, bfr[nt], acc[0][nt], 0, 0, 0);
        __syncthreads();
    }

#pragma unroll
    for (int nt = 0; nt < NT; ++nt)
#pragma unroll
        for (int i = 0; i < 4; ++i) {
            int row = bm + w * WTM + (l >> 4) * 4 + i;
            int col = nt * 16 + lr;
            if (row < M) Cb[(size_t)row * BN + col] = f2bf(acc[0][nt][i]);
        }
}

// ---------------- layer-1 aggregation + bias + relu (fp8 in / bf16 out) ----------------
__global__ __launch_bounds__(256) void k_agg1(const uchar* __restrict__ h8,
                                              const int* __restrict__ rowstart,
                                              const int2* __restrict__ er,
                                              const float* __restrict__ dinv,
                                              const float* __restrict__ b1,
                                              ushort* __restrict__ out) {
    int wave = threadIdx.x >> 6;
    int lane = threadIdx.x & 63;
    int n = blockIdx.x * 4 + wave;
    if (n >= NODES) return;
    float4 acc = make_float4(0.f, 0.f, 0.f, 0.f);
    int e0 = rowstart[n], e1 = rowstart[n + 1];
    int e = e0;
#define A1_STEP(q, qv)                                                        \
    {                                                                         \
        float w = __int_as_float((q).y);                                      \
        f32x2 lo = __builtin_amdgcn_cvt_pk_f32_fp8((int)(qv), false);         \
        f32x2 hi = __builtin_amdgcn_cvt_pk_f32_fp8((int)(qv), true);          \
        acc.x = fmaf(w, lo[0], acc.x);                                        \
        acc.y = fmaf(w, lo[1], acc.y);                                        \
        acc.z = fmaf(w, hi[0], acc.z);                                        \
        acc.w = fmaf(w, hi[1], acc.w);                                        \
    }
    for (; e + 8 <= e1; e += 8) {
        int2 q0 = er[e],     q1 = er[e + 1], q2 = er[e + 2], q3 = er[e + 3];
        int2 q4 = er[e + 4], q5 = er[e + 5], q6 = er[e + 6], q7 = er[e + 7];
        uint v0 = *(const uint*)(h8 + (size_t)q0.x * 256 + lane * 4);
        uint v1 = *(const uint*)(h8 + (size_t)q1.x * 256 + lane * 4);
        uint v2 = *(const uint*)(h8 + (size_t)q2.x * 256 + lane * 4);
        uint v3 = *(const uint*)(h8 + (size_t)q3.x * 256 + lane * 4);
        uint v4 = *(const uint*)(h8 + (size_t)q4.x * 256 + lane * 4);
        uint v5 = *(const uint*)(h8 + (size_t)q5.x * 256 + lane * 4);
        uint v6 = *(const uint*)(h8 + (size_t)q6.x * 256 + lane * 4);
        uint v7 = *(const uint*)(h8 + (size_t)q7.x * 256 + lane * 4);
        A1_STEP(q0, v0) A1_STEP(q1, v1) A1_STEP(q2, v2) A1_STEP(q3, v3)
        A1_STEP(q4, v4) A1_STEP(q5, v5) A1_STEP(q6, v6) A1_STEP(q7, v7)
    }
    for (; e < e1; ++e) {
        int2 q = er[e];
        uint v = *(const uint*)(h8 + (size_t)q.x * 256 + lane * 4);
        A1_STEP(q, v)
    }
#undef A1_STEP
    float dn = dinv[n];
    float s2 = dn * dn;
    uint qs = *(const uint*)(h8 + (size_t)n * 256 + lane * 4);
    f32x2 slo = __builtin_amdgcn_cvt_pk_f32_fp8((int)qs, false);
    f32x2 shi = __builtin_amdgcn_cvt_pk_f32_fp8((int)qs, true);
    float4 bb = *(const float4*)(b1 + lane * 4);
    ushort4 r;
    r.x = f2bf(fmaxf(fmaf(acc.x, dn, fmaf(slo[0], s2, bb.x)), 0.f));
    r.y = f2bf(fmaxf(fmaf(acc.y, dn, fmaf(slo[1], s2, bb.y)), 0.f));
    r.z = f2bf(fmaxf(fmaf(acc.z, dn, fmaf(shi[0], s2, bb.z)), 0.f));
    r.w = f2bf(fmaxf(fmaf(acc.w, dn, fmaf(shi[1], s2, bb.w)), 0.f));
    *(ushort4*)(out + (size_t)n * 256 + lane * 4) = r;
}

// ---------------- layer-2 aggregation + bias + log_softmax (bf16 h2) ----------------
__global__ __launch_bounds__(256) void k_agg2(const ushort* __restrict__ h,
                                              const int* __restrict__ rowstart,
                                              const int2* __restrict__ er,
                                              const float* __restrict__ dinv,
                                              const float* __restrict__ b2,
                                              float* __restrict__ out) {
    int wave = threadIdx.x >> 6;
    int lane = threadIdx.x & 63;
    int n = blockIdx.x * 4 + wave;
    if (n >= NODES) return;
    float acc = 0.f;
    int e0 = rowstart[n], e1 = rowstart[n + 1];
    int e = e0;
    for (; e + 8 <= e1; e += 8) {
        int2 q0 = er[e],     q1 = er[e + 1], q2 = er[e + 2], q3 = er[e + 3];
        int2 q4 = er[e + 4], q5 = er[e + 5], q6 = er[e + 6], q7 = er[e + 7];
        ushort v0 = h[(size_t)q0.x * 64 + lane];
        ushort v1 = h[(size_t)q1.x * 64 + lane];
        ushort v2 = h[(size_t)q2.x * 64 + lane];
        ushort v3 = h[(size_t)q3.x * 64 + lane];
        ushort v4 = h[(size_t)q4.x * 64 + lane];
        ushort v5 = h[(size_t)q5.x * 64 + lane];
        ushort v6 = h[(size_t)q6.x * 64 + lane];
        ushort v7 = h[(size_t)q7.x * 64 + lane];
        acc = fmaf(__int_as_float(q0.y), bf2f(v0), acc);
        acc = fmaf(__int_as_float(q1.y), bf2f(v1), acc);
        acc = fmaf(__int_as_float(q2.y), bf2f(v2), acc);
        acc = fmaf(__int_as_float(q3.y), bf2f(v3), acc);
        acc = fmaf(__int_as_float(q4.y), bf2f(v4), acc);
        acc = fmaf(__int_as_float(q5.y), bf2f(v5), acc);
        acc = fmaf(__int_as_float(q6.y), bf2f(v6), acc);
        acc = fmaf(__int_as_float(q7.y), bf2f(v7), acc);
    }
    for (; e < e1; ++e) {
        int2 q = er[e];
        acc = fmaf(__int_as_float(q.y), bf2f(h[(size_t)q.x * 64 + lane]), acc);
    }
    float dn = dinv[n];
    float r = fmaf(acc, dn, fmaf(bf2f(h[(size_t)n * 64 + lane]), dn * dn, b2[lane]));
    float m = r;
#pragma unroll
    for (int off = 32; off; off >>= 1) m = fmaxf(m, __shfl_xor(m, off));
    float ex = __expf(r - m);
    float ssum = ex;
#pragma unroll
    for (int off = 32; off; off >>= 1) ssum += __shfl_xor(ssum, off);
    out[(size_t)n * 64 + lane] = r - m - __logf(ssum);
}

// ---------------- launch ----------------

extern "C" void kernel_launch(void* const* d_in, const int* in_sizes, int n_in,
                              void* d_out, int out_size, void* d_ws, size_t ws_size,
                              hipStream_t stream) {
    const float* x  = (const float*)d_in[0];
    const float* W1 = (const float*)d_in[1];
    const float* b1 = (const float*)d_in[2];
    const float* W2 = (const float*)d_in[3];
    const float* b2 = (const float*)d_in[4];
    const int*   ei = (const int*)d_in[5];
    int E = in_sizes[5] / 2;
    const int* src = ei;
    const int* dst = ei + E;
    float* out = (float*)d_out;

    char* wsp = (char*)d_ws;
    auto alloc = [&](size_t bytes) {
        char* p = wsp;
        wsp += (bytes + 255) & ~(size_t)255;
        return p;
    };
    int*    degcnt   = (int*)alloc((size_t)NODES * 4);
    float*  dinv     = (float*)alloc((size_t)NODES * 4);
    int*    rowstart = (int*)alloc((size_t)(NODES + 1) * 4);
    int*    cursor   = (int*)alloc((size_t)NODES * 4);
    int*    bsum     = (int*)alloc((size_t)NB * 4);
    int*    boff     = (int*)alloc((size_t)NB * 4);
    int2*   erec     = (int2*)alloc((size_t)E * 8);
    ushort* w1t      = (ushort*)alloc((size_t)256 * 512 * 2);   // W1^T bf16 [256][512]
    ushort* w2t      = (ushort*)alloc((size_t)64 * 256 * 2);    // W2^T bf16 [64][256]
    uchar*  h1f8     = (uchar*)alloc((size_t)NODES * 256);      // fp8 h1 (12.8 MB)
    ushort* h1ab     = (ushort*)alloc((size_t)NODES * 256 * 2); // bf16 relu(agg1)
    ushort* h2b      = (ushort*)alloc((size_t)NODES * 64 * 2);  // bf16 h2

    hipMemsetAsync(degcnt, 0, (size_t)NODES * 4, stream);
    hipMemsetAsync(cursor, 0, (size_t)NODES * 4, stream);

    k_count<<<(E + 255) / 256, 256, 0, stream>>>(dst, E, degcnt);
    k_bsum<<<NB, 256, 0, stream>>>(degcnt, bsum);
    k_bscan<<<1, 256, 0, stream>>>(bsum, boff, NB);
    k_scan3<<<NB, 256, 0, stream>>>(degcnt, boff, rowstart, dinv);

    // weight casts (tiny; W1 must precede fused gemm)
    k_castT<<<(512 * 256 + 255) / 256, 256, 0, stream>>>(W1, w1t, 512, 256);
    k_castT<<<(256 * 64 + 255) / 256, 256, 0, stream>>>(W2, w2t, 256, 64);

    // fused: GEMM1 (x@W1 -> fp8) ∥ edge scatter
    int gemmBlocks = (NODES + 63) / 64;                 // 782
    int scatBlocks = (E + 2047) / 2048;                 // 782
    k_gemm1_scatter<<<gemmBlocks + scatBlocks, 256, 0, stream>>>(
        x, w1t, h1f8, NODES, 512,
        src, dst, E, rowstart, cursor, dinv, erec, gemmBlocks);

    k_agg1<<<(NODES + 3) / 4, 256, 0, stream>>>(h1f8, rowstart, erec, dinv, b1, h1ab);

    // layer 2: h2 = h1a @ W2 -> bf16
    k_gemm2<<<(NODES + 63) / 64, 256, 0, stream>>>(h1ab, w2t, h2b, NODES, 256);
    k_agg2<<<(NODES + 3) / 4, 256, 0, stream>>>(h2b, rowstart, erec, dinv, b2, out);
}

// Round 9
// 260.635 us; speedup vs baseline: 2.9281x; 1.3823x over previous
//
#include <hip/hip_runtime.h>

#define NODES 50000
#define NBIN 196          // ceil(50000/256) dst-bins of 256 nodes
#define EPB 2048          // edges per partition block

typedef __attribute__((ext_vector_type(8))) short short8;
typedef __attribute__((ext_vector_type(4))) float f32x4;
typedef __attribute__((ext_vector_type(2))) float f32x2;

__device__ __forceinline__ ushort f2bf(float f) {
    uint u = __float_as_uint(f);
    uint r = (u + 0x7fffu + ((u >> 16) & 1u)) >> 16;
    return (ushort)r;
}
__device__ __forceinline__ float bf2f(ushort u) {
    return __uint_as_float(((uint)u) << 16);
}
__device__ __forceinline__ uchar f2fp8(float f) {
    return (uchar)(__builtin_amdgcn_cvt_pk_fp8_f32(f, f, 0, false) & 0xff);
}

// ---------------- atomic-free two-level CSR build ----------------

// C1: per-block per-bin histogram (LDS atomics only)
__global__ __launch_bounds__(256) void k_hist(const int* __restrict__ dst, int E,
                                              int* __restrict__ hist, int nblk) {
    __shared__ int h[NBIN];
    int t = threadIdx.x;
    for (int i = t; i < NBIN; i += 256) h[i] = 0;
    __syncthreads();
    int base = blockIdx.x * EPB;
#pragma unroll
    for (int i = 0; i < EPB / 256; ++i) {
        int e = base + i * 256 + t;
        if (e < E) atomicAdd(&h[dst[e] >> 8], 1);
    }
    __syncthreads();
    for (int i = t; i < NBIN; i += 256) hist[i * nblk + blockIdx.x] = h[i];
}

// C2a: per-bin exclusive scan over blocks -> offl; bin totals -> btot
__global__ __launch_bounds__(1024) void k_scanbin(const int* __restrict__ hist,
                                                  int* __restrict__ offl,
                                                  int* __restrict__ btot, int nblk) {
    __shared__ int s[1024];
    int b = blockIdx.x, t = threadIdx.x;
    int v = (t < nblk) ? hist[b * nblk + t] : 0;
    s[t] = v;
    __syncthreads();
    for (int off = 1; off < 1024; off <<= 1) {
        int u = (t >= off) ? s[t - off] : 0;
        __syncthreads();
        s[t] += u;
        __syncthreads();
    }
    if (t < nblk) offl[b * nblk + t] = s[t] - v;
    if (t == 1023) btot[b] = s[1023];
}

// C2b: scan bin totals -> binoff[NBIN+1]; also rowstart[NODES]=E
__global__ __launch_bounds__(256) void k_scanoff(const int* __restrict__ btot,
                                                 int* __restrict__ binoff,
                                                 int* __restrict__ rowstart, int E) {
    __shared__ int s[256];
    int t = threadIdx.x;
    int v = (t < NBIN) ? btot[t] : 0;
    s[t] = v;
    __syncthreads();
    for (int off = 1; off < 256; off <<= 1) {
        int u = (t >= off) ? s[t - off] : 0;
        __syncthreads();
        s[t] += u;
        __syncthreads();
    }
    if (t < NBIN) binoff[t] = s[t] - v;
    if (t == 0) { binoff[NBIN] = E; rowstart[NODES] = E; }
}

// C3: partition edges into bin-contiguous tmp (reserved ranges, no global atomics)
__global__ __launch_bounds__(256) void k_part(const int* __restrict__ src,
                                              const int* __restrict__ dst, int E,
                                              const int* __restrict__ offl,
                                              const int* __restrict__ binoff, int nblk,
                                              int2* __restrict__ tmp) {
    __shared__ int cur[NBIN];
    int t = threadIdx.x, blk = blockIdx.x;
    for (int i = t; i < NBIN; i += 256) cur[i] = binoff[i] + offl[i * nblk + blk];
    __syncthreads();
    int base = blk * EPB;
#pragma unroll
    for (int i = 0; i < EPB / 256; ++i) {
        int e = base + i * 256 + t;
        if (e < E) {
            int d = dst[e];
            int p = atomicAdd(&cur[d >> 8], 1);
            tmp[p] = make_int2(src[e], d);
        }
    }
}

// D: one block per bin -> node counts, rowstart, dinv, final in-window scatter
__global__ __launch_bounds__(256) void k_csr(const int2* __restrict__ tmp,
                                             const int* __restrict__ binoff,
                                             int* __restrict__ rowstart,
                                             float* __restrict__ dinv,
                                             int* __restrict__ esrc) {
    __shared__ int ncnt[256], nst[256];
    int b = blockIdx.x, t = threadIdx.x;
    int e0 = binoff[b], e1 = binoff[b + 1];
    int nb0 = b << 8;
    int nn = min(256, NODES - nb0);
    ncnt[t] = 0;
    __syncthreads();
    for (int e = e0 + t; e < e1; e += 256) atomicAdd(&ncnt[tmp[e].y - nb0], 1);
    __syncthreads();
    int v = ncnt[t];
    nst[t] = v;
    __syncthreads();
    for (int off = 1; off < 256; off <<= 1) {
        int u = (t >= off) ? nst[t - off] : 0;
        __syncthreads();
        nst[t] += u;
        __syncthreads();
    }
    int excl = nst[t] - v;
    if (t < nn) {
        rowstart[nb0 + t] = e0 + excl;
        dinv[nb0 + t] = rsqrtf(1.0f + (float)v);
    }
    __syncthreads();
    ncnt[t] = e0 + excl;   // reuse as global-positioned cursor
    __syncthreads();
    for (int e = e0 + t; e < e1; e += 256) {
        int2 q = tmp[e];
        int p = atomicAdd(&ncnt[q.y - nb0], 1);
        esrc[p] = q.x;
    }
}

// E: per-edge weight = dinv[src]
__global__ void k_wfill(const int* __restrict__ esrc, const float* __restrict__ dinv,
                        float* __restrict__ ew, int E) {
    int e = blockIdx.x * blockDim.x + threadIdx.x;
    if (e < E) ew[e] = dinv[esrc[e]];
}

// ---------------- casts ----------------

__global__ void k_castT(const float* __restrict__ in, ushort* __restrict__ out, int R, int C) {
    int i = blockIdx.x * blockDim.x + threadIdx.x;
    if (i >= R * C) return;
    int r = i / C, c = i % C;
    out[(size_t)c * R + r] = f2bf(in[i]);
}

// ---------------- GEMM1: x[M,512] @ W1t[256,512]^T -> fp8 h1 ----------------
// BM=64, BN=256, 4 waves (WN=4), SA=40.
__global__ __launch_bounds__(256) void k_gemm1(const float* __restrict__ x,
                                               const ushort* __restrict__ w1t,
                                               uchar* __restrict__ h1f8, int M, int K) {
    constexpr int BM = 64, BN = 256;
    constexpr int MT = 4, NT = 4;   // wave: 64 rows x 64 cols
    constexpr int SA = 40;
    __shared__ ushort As[BM * SA];
    __shared__ ushort Bs[BN * SA];

    int t = threadIdx.x;
    int w = t >> 6, l = t & 63;
    int bm = blockIdx.x * BM;
    int lr = l & 15, lk = (l >> 4) * 8;

    f32x4 acc[MT][NT] = {};
    const int ACH = BM * 4;
    const int BCH = BN * 4;

    for (int k0 = 0; k0 < K; k0 += 32) {
        for (int c = t; c < ACH + BCH; c += 256) {
            if (c < ACH) {
                int row = c >> 2, seg = c & 3;
                int gr = bm + row;
                ushort r[8] = {0, 0, 0, 0, 0, 0, 0, 0};
                if (gr < M) {
                    const float* p = x + (size_t)gr * K + k0 + seg * 8;
                    float4 a = *(const float4*)p;
                    float4 b = *(const float4*)(p + 4);
                    r[0] = f2bf(a.x); r[1] = f2bf(a.y); r[2] = f2bf(a.z); r[3] = f2bf(a.w);
                    r[4] = f2bf(b.x); r[5] = f2bf(b.y); r[6] = f2bf(b.z); r[7] = f2bf(b.w);
                }
                *(int4*)(&As[row * SA + seg * 8]) = *(int4*)r;
            } else {
                int cc = c - ACH;
                int row = cc >> 2, seg = cc & 3;
                int4 v = *(const int4*)(w1t + (size_t)row * K + k0 + seg * 8);
                *(int4*)(&Bs[row * SA + seg * 8]) = v;
            }
        }
        __syncthreads();
        short8 af[MT], bfr[NT];
#pragma unroll
        for (int mt = 0; mt < MT; ++mt)
            af[mt] = *(const short8*)(&As[(mt * 16 + lr) * SA + lk]);
#pragma unroll
        for (int nt = 0; nt < NT; ++nt)
            bfr[nt] = *(const short8*)(&Bs[(w * 64 + nt * 16 + lr) * SA + lk]);
#pragma unroll
        for (int mt = 0; mt < MT; ++mt)
#pragma unroll
            for (int nt = 0; nt < NT; ++nt)
                acc[mt][nt] = __builtin_amdgcn_mfma_f32_16x16x32_bf16(af[mt], bfr[nt], acc[mt][nt], 0, 0, 0);
        __syncthreads();
    }

#pragma unroll
    for (int mt = 0; mt < MT; ++mt)
#pragma unroll
        for (int nt = 0; nt < NT; ++nt)
#pragma unroll
            for (int i = 0; i < 4; ++i) {
                int row = bm + mt * 16 + (l >> 4) * 4 + i;
                int col = w * 64 + nt * 16 + lr;
                if (row < M) h1f8[(size_t)row * BN + col] = f2fp8(acc[mt][nt][i]);
            }
}

// ---------------- GEMM2: h1a[M,256] @ W2t[64,256]^T -> bf16 h2 ----------------
__global__ __launch_bounds__(256) void k_gemm2(const ushort* __restrict__ A,
                                               const ushort* __restrict__ Bt,
                                               ushort* __restrict__ Cb,
                                               int M, int K) {
    constexpr int BM = 64, BN = 64;
    constexpr int NT = 4;
    constexpr int SA = 40;
    __shared__ ushort As[BM * SA];
    __shared__ ushort Bs[BN * SA];

    int t = threadIdx.x;
    int w = t >> 6, l = t & 63;
    int bm = blockIdx.x * BM;
    int lr = l & 15, lk = (l >> 4) * 8;

    f32x4 acc[NT] = {};
    const int ACH = BM * 4;
    const int BCH = BN * 4;

    for (int k0 = 0; k0 < K; k0 += 32) {
        for (int c = t; c < ACH + BCH; c += 256) {
            if (c < ACH) {
                int row = c >> 2, seg = c & 3;
                int gr = bm + row;
                int4 v = make_int4(0, 0, 0, 0);
                if (gr < M) v = *(const int4*)(A + (size_t)gr * K + k0 + seg * 8);
                *(int4*)(&As[row * SA + seg * 8]) = v;
            } else {
                int cc = c - ACH;
                int row = cc >> 2, seg = cc & 3;
                int4 v = *(const int4*)(Bt + (size_t)row * K + k0 + seg * 8);
                *(int4*)(&Bs[row * SA + seg * 8]) = v;
            }
        }
        __syncthreads();
        short8 af = *(const short8*)(&As[(w * 16 + lr) * SA + lk]);
        short8 bfr[NT];
#pragma unroll
        for (int nt = 0; nt < NT; ++nt)
            bfr[nt] = *(const short8*)(&Bs[(nt * 16 + lr) * SA + lk]);
#pragma unroll
        for (int nt = 0; nt < NT; ++nt)
            acc[nt] = __builtin_amdgcn_mfma_f32_16x16x32_bf16(af, bfr[nt], acc[nt], 0, 0, 0);
        __syncthreads();
    }

#pragma unroll
    for (int nt = 0; nt < NT; ++nt)
#pragma unroll
        for (int i = 0; i < 4; ++i) {
            int row = bm + w * 16 + (l >> 4) * 4 + i;
            int col = nt * 16 + lr;
            if (row < M) Cb[(size_t)row * BN + col] = f2bf(acc[nt][i]);
        }
}

// ---------------- layer-1 aggregation + bias + relu (fp8 in / bf16 out) ----------------
__global__ __launch_bounds__(256) void k_agg1(const uchar* __restrict__ h8,
                                              const int* __restrict__ rowstart,
                                              const int* __restrict__ esrc,
                                              const float* __restrict__ ew,
                                              const float* __restrict__ dinv,
                                              const float* __restrict__ b1,
                                              ushort* __restrict__ out) {
    int wave = threadIdx.x >> 6;
    int lane = threadIdx.x & 63;
    int n = blockIdx.x * 4 + wave;
    if (n >= NODES) return;
    float4 acc = make_float4(0.f, 0.f, 0.f, 0.f);
    int e0 = rowstart[n], e1 = rowstart[n + 1];
    int e = e0;
#define A1_STEP(wt, qv)                                                       \
    {                                                                         \
        f32x2 lo = __builtin_amdgcn_cvt_pk_f32_fp8((int)(qv), false);         \
        f32x2 hi = __builtin_amdgcn_cvt_pk_f32_fp8((int)(qv), true);          \
        acc.x = fmaf(wt, lo[0], acc.x);                                       \
        acc.y = fmaf(wt, lo[1], acc.y);                                       \
        acc.z = fmaf(wt, hi[0], acc.z);                                       \
        acc.w = fmaf(wt, hi[1], acc.w);                                       \
    }
    for (; e + 8 <= e1; e += 8) {
        int s0 = esrc[e],     s1 = esrc[e + 1], s2 = esrc[e + 2], s3 = esrc[e + 3];
        int s4 = esrc[e + 4], s5 = esrc[e + 5], s6 = esrc[e + 6], s7 = esrc[e + 7];
        float w0 = ew[e],     w1 = ew[e + 1], w2 = ew[e + 2], w3 = ew[e + 3];
        float w4 = ew[e + 4], w5 = ew[e + 5], w6 = ew[e + 6], w7 = ew[e + 7];
        uint v0 = *(const uint*)(h8 + (size_t)s0 * 256 + lane * 4);
        uint v1 = *(const uint*)(h8 + (size_t)s1 * 256 + lane * 4);
        uint v2 = *(const uint*)(h8 + (size_t)s2 * 256 + lane * 4);
        uint v3 = *(const uint*)(h8 + (size_t)s3 * 256 + lane * 4);
        uint v4 = *(const uint*)(h8 + (size_t)s4 * 256 + lane * 4);
        uint v5 = *(const uint*)(h8 + (size_t)s5 * 256 + lane * 4);
        uint v6 = *(const uint*)(h8 + (size_t)s6 * 256 + lane * 4);
        uint v7 = *(const uint*)(h8 + (size_t)s7 * 256 + lane * 4);
        A1_STEP(w0, v0) A1_STEP(w1, v1) A1_STEP(w2, v2) A1_STEP(w3, v3)
        A1_STEP(w4, v4) A1_STEP(w5, v5) A1_STEP(w6, v6) A1_STEP(w7, v7)
    }
    for (; e < e1; ++e) {
        int s = esrc[e];
        float wt = ew[e];
        uint v = *(const uint*)(h8 + (size_t)s * 256 + lane * 4);
        A1_STEP(wt, v)
    }
#undef A1_STEP
    float dn = dinv[n];
    float s2v = dn * dn;
    uint qs = *(const uint*)(h8 + (size_t)n * 256 + lane * 4);
    f32x2 slo = __builtin_amdgcn_cvt_pk_f32_fp8((int)qs, false);
    f32x2 shi = __builtin_amdgcn_cvt_pk_f32_fp8((int)qs, true);
    float4 bb = *(const float4*)(b1 + lane * 4);
    ushort4 r;
    r.x = f2bf(fmaxf(fmaf(acc.x, dn, fmaf(slo[0], s2v, bb.x)), 0.f));
    r.y = f2bf(fmaxf(fmaf(acc.y, dn, fmaf(slo[1], s2v, bb.y)), 0.f));
    r.z = f2bf(fmaxf(fmaf(acc.z, dn, fmaf(shi[0], s2v, bb.z)), 0.f));
    r.w = f2bf(fmaxf(fmaf(acc.w, dn, fmaf(shi[1], s2v, bb.w)), 0.f));
    *(ushort4*)(out + (size_t)n * 256 + lane * 4) = r;
}

// ---------------- layer-2 aggregation + bias + log_softmax (bf16 h2) ----------------
__global__ __launch_bounds__(256) void k_agg2(const ushort* __restrict__ h,
                                              const int* __restrict__ rowstart,
                                              const int* __restrict__ esrc,
                                              const float* __restrict__ ew,
                                              const float* __restrict__ dinv,
                                              const float* __restrict__ b2,
                                              float* __restrict__ out) {
    int wave = threadIdx.x >> 6;
    int lane = threadIdx.x & 63;
    int n = blockIdx.x * 4 + wave;
    if (n >= NODES) return;
    float acc = 0.f;
    int e0 = rowstart[n], e1 = rowstart[n + 1];
    int e = e0;
    for (; e + 8 <= e1; e += 8) {
        int s0 = esrc[e],     s1 = esrc[e + 1], s2 = esrc[e + 2], s3 = esrc[e + 3];
        int s4 = esrc[e + 4], s5 = esrc[e + 5], s6 = esrc[e + 6], s7 = esrc[e + 7];
        float w0 = ew[e],     w1 = ew[e + 1], w2 = ew[e + 2], w3 = ew[e + 3];
        float w4 = ew[e + 4], w5 = ew[e + 5], w6 = ew[e + 6], w7 = ew[e + 7];
        float v0 = bf2f(h[(size_t)s0 * 64 + lane]);
        float v1 = bf2f(h[(size_t)s1 * 64 + lane]);
        float v2 = bf2f(h[(size_t)s2 * 64 + lane]);
        float v3 = bf2f(h[(size_t)s3 * 64 + lane]);
        float v4 = bf2f(h[(size_t)s4 * 64 + lane]);
        float v5 = bf2f(h[(size_t)s5 * 64 + lane]);
        float v6 = bf2f(h[(size_t)s6 * 64 + lane]);
        float v7 = bf2f(h[(size_t)s7 * 64 + lane]);
        acc = fmaf(w0, v0, acc); acc = fmaf(w1, v1, acc);
        acc = fmaf(w2, v2, acc); acc = fmaf(w3, v3, acc);
        acc = fmaf(w4, v4, acc); acc = fmaf(w5, v5, acc);
        acc = fmaf(w6, v6, acc); acc = fmaf(w7, v7, acc);
    }
    for (; e < e1; ++e)
        acc = fmaf(ew[e], bf2f(h[(size_t)esrc[e] * 64 + lane]), acc);
    float dn = dinv[n];
    float r = fmaf(acc, dn, fmaf(bf2f(h[(size_t)n * 64 + lane]), dn * dn, b2[lane]));
    float m = r;
#pragma unroll
    for (int off = 32; off; off >>= 1) m = fmaxf(m, __shfl_xor(m, off));
    float ex = __expf(r - m);
    float ssum = ex;
#pragma unroll
    for (int off = 32; off; off >>= 1) ssum += __shfl_xor(ssum, off);
    out[(size_t)n * 64 + lane] = r - m - __logf(ssum);
}

// ---------------- launch ----------------

extern "C" void kernel_launch(void* const* d_in, const int* in_sizes, int n_in,
                              void* d_out, int out_size, void* d_ws, size_t ws_size,
                              hipStream_t stream) {
    const float* x  = (const float*)d_in[0];
    const float* W1 = (const float*)d_in[1];
    const float* b1 = (const float*)d_in[2];
    const float* W2 = (const float*)d_in[3];
    const float* b2 = (const float*)d_in[4];
    const int*   ei = (const int*)d_in[5];
    int E = in_sizes[5] / 2;
    const int* src = ei;
    const int* dst = ei + E;
    float* out = (float*)d_out;

    int nblk = (E + EPB - 1) / EPB;   // 782

    char* wsp = (char*)d_ws;
    auto alloc = [&](size_t bytes) {
        char* p = wsp;
        wsp += (bytes + 255) & ~(size_t)255;
        return p;
    };
    int*    hist     = (int*)alloc((size_t)NBIN * nblk * 4);
    int*    offl     = (int*)alloc((size_t)NBIN * nblk * 4);
    int*    btot     = (int*)alloc((size_t)NBIN * 4);
    int*    binoff   = (int*)alloc((size_t)(NBIN + 1) * 4);
    int*    rowstart = (int*)alloc((size_t)(NODES + 1) * 4);
    float*  dinv     = (float*)alloc((size_t)NODES * 4);
    int2*   tmp      = (int2*)alloc((size_t)E * 8);
    int*    esrc     = (int*)alloc((size_t)E * 4);
    float*  ew       = (float*)alloc((size_t)E * 4);
    ushort* w1t      = (ushort*)alloc((size_t)256 * 512 * 2);
    ushort* w2t      = (ushort*)alloc((size_t)64 * 256 * 2);
    uchar*  h1f8     = (uchar*)alloc((size_t)NODES * 256);
    ushort* h1ab     = (ushort*)alloc((size_t)NODES * 256 * 2);
    ushort* h2b      = (ushort*)alloc((size_t)NODES * 64 * 2);

    // ---- CSR build (no global atomics, dense writes) ----
    k_hist<<<nblk, 256, 0, stream>>>(dst, E, hist, nblk);
    k_scanbin<<<NBIN, 1024, 0, stream>>>(hist, offl, btot, nblk);
    k_scanoff<<<1, 256, 0, stream>>>(btot, binoff, rowstart, E);
    k_part<<<nblk, 256, 0, stream>>>(src, dst, E, offl, binoff, nblk, tmp);
    k_csr<<<NBIN, 256, 0, stream>>>(tmp, binoff, rowstart, dinv, esrc);
    k_wfill<<<(E + 255) / 256, 256, 0, stream>>>(esrc, dinv, ew, E);

    // ---- weight casts ----
    k_castT<<<(512 * 256 + 255) / 256, 256, 0, stream>>>(W1, w1t, 512, 256);
    k_castT<<<(256 * 64 + 255) / 256, 256, 0, stream>>>(W2, w2t, 256, 64);

    // ---- layer 1 ----
    k_gemm1<<<(NODES + 63) / 64, 256, 0, stream>>>(x, w1t, h1f8, NODES, 512);
    k_agg1<<<(NODES + 3) / 4, 256, 0, stream>>>(h1f8, rowstart, esrc, ew, dinv, b1, h1ab);

    // ---- layer 2 ----
    k_gemm2<<<(NODES + 63) / 64, 256, 0, stream>>>(h1ab, w2t, h2b, NODES, 256);
    k_agg2<<<(NODES + 3) / 4, 256, 0, stream>>>(h2b, rowstart, esrc, ew, dinv, b2, out);
}

// Round 10
// 247.417 us; speedup vs baseline: 3.0845x; 1.0534x over previous
//
#include <hip/hip_runtime.h>

#define NODES 50000
#define NBIN 196          // ceil(50000/256) dst-bins of 256 nodes
#define EPB 2048          // edges per partition block

typedef __attribute__((ext_vector_type(8))) short short8;
typedef __attribute__((ext_vector_type(4))) float f32x4;
typedef __attribute__((ext_vector_type(2))) float f32x2;

__device__ __forceinline__ ushort f2bf(float f) {
    uint u = __float_as_uint(f);
    uint r = (u + 0x7fffu + ((u >> 16) & 1u)) >> 16;
    return (ushort)r;
}
__device__ __forceinline__ float bf2f(ushort u) {
    return __uint_as_float(((uint)u) << 16);
}
__device__ __forceinline__ uchar f2fp8(float f) {
    return (uchar)(__builtin_amdgcn_cvt_pk_fp8_f32(f, f, 0, false) & 0xff);
}
// HW packed f32x2 -> bf16x2 (RNE), one VALU op
__device__ __forceinline__ uint cvtpk_bf16(float lo, float hi) {
    uint r;
    asm("v_cvt_pk_bf16_f32 %0, %1, %2" : "=v"(r) : "v"(lo), "v"(hi));
    return r;
}

// ---------------- atomic-free two-level CSR build ----------------

__global__ __launch_bounds__(256) void k_hist(const int* __restrict__ dst, int E,
                                              int* __restrict__ hist, int nblk) {
    __shared__ int h[NBIN];
    int t = threadIdx.x;
    for (int i = t; i < NBIN; i += 256) h[i] = 0;
    __syncthreads();
    int base = blockIdx.x * EPB;
#pragma unroll
    for (int i = 0; i < EPB / 256; ++i) {
        int e = base + i * 256 + t;
        if (e < E) atomicAdd(&h[dst[e] >> 8], 1);
    }
    __syncthreads();
    for (int i = t; i < NBIN; i += 256) hist[i * nblk + blockIdx.x] = h[i];
}

__global__ __launch_bounds__(1024) void k_scanbin(const int* __restrict__ hist,
                                                  int* __restrict__ offl,
                                                  int* __restrict__ btot, int nblk) {
    __shared__ int s[1024];
    int b = blockIdx.x, t = threadIdx.x;
    int v = (t < nblk) ? hist[b * nblk + t] : 0;
    s[t] = v;
    __syncthreads();
    for (int off = 1; off < 1024; off <<= 1) {
        int u = (t >= off) ? s[t - off] : 0;
        __syncthreads();
        s[t] += u;
        __syncthreads();
    }
    if (t < nblk) offl[b * nblk + t] = s[t] - v;
    if (t == 1023) btot[b] = s[1023];
}

__global__ __launch_bounds__(256) void k_scanoff(const int* __restrict__ btot,
                                                 int* __restrict__ binoff,
                                                 int* __restrict__ rowstart, int E) {
    __shared__ int s[256];
    int t = threadIdx.x;
    int v = (t < NBIN) ? btot[t] : 0;
    s[t] = v;
    __syncthreads();
    for (int off = 1; off < 256; off <<= 1) {
        int u = (t >= off) ? s[t - off] : 0;
        __syncthreads();
        s[t] += u;
        __syncthreads();
    }
    if (t < NBIN) binoff[t] = s[t] - v;
    if (t == 0) { binoff[NBIN] = E; rowstart[NODES] = E; }
}

__global__ __launch_bounds__(256) void k_part(const int* __restrict__ src,
                                              const int* __restrict__ dst, int E,
                                              const int* __restrict__ offl,
                                              const int* __restrict__ binoff, int nblk,
                                              int2* __restrict__ tmp) {
    __shared__ int cur[NBIN];
    int t = threadIdx.x, blk = blockIdx.x;
    for (int i = t; i < NBIN; i += 256) cur[i] = binoff[i] + offl[i * nblk + blk];
    __syncthreads();
    int base = blk * EPB;
#pragma unroll
    for (int i = 0; i < EPB / 256; ++i) {
        int e = base + i * 256 + t;
        if (e < E) {
            int d = dst[e];
            int p = atomicAdd(&cur[d >> 8], 1);
            tmp[p] = make_int2(src[e], d);
        }
    }
}

__global__ __launch_bounds__(256) void k_csr(const int2* __restrict__ tmp,
                                             const int* __restrict__ binoff,
                                             int* __restrict__ rowstart,
                                             float* __restrict__ dinv,
                                             int* __restrict__ esrc) {
    __shared__ int ncnt[256], nst[256];
    int b = blockIdx.x, t = threadIdx.x;
    int e0 = binoff[b], e1 = binoff[b + 1];
    int nb0 = b << 8;
    int nn = min(256, NODES - nb0);
    ncnt[t] = 0;
    __syncthreads();
    for (int e = e0 + t; e < e1; e += 256) atomicAdd(&ncnt[tmp[e].y - nb0], 1);
    __syncthreads();
    int v = ncnt[t];
    nst[t] = v;
    __syncthreads();
    for (int off = 1; off < 256; off <<= 1) {
        int u = (t >= off) ? nst[t - off] : 0;
        __syncthreads();
        nst[t] += u;
        __syncthreads();
    }
    int excl = nst[t] - v;
    if (t < nn) {
        rowstart[nb0 + t] = e0 + excl;
        dinv[nb0 + t] = rsqrtf(1.0f + (float)v);
    }
    __syncthreads();
    ncnt[t] = e0 + excl;
    __syncthreads();
    for (int e = e0 + t; e < e1; e += 256) {
        int2 q = tmp[e];
        int p = atomicAdd(&ncnt[q.y - nb0], 1);
        esrc[p] = q.x;
    }
}

__global__ void k_wfill(const int* __restrict__ esrc, const float* __restrict__ dinv,
                        float* __restrict__ ew, int E) {
    int e = blockIdx.x * blockDim.x + threadIdx.x;
    if (e < E) ew[e] = dinv[esrc[e]];
}

// ---------------- casts ----------------

__global__ void k_castT(const float* __restrict__ in, ushort* __restrict__ out, int R, int C) {
    int i = blockIdx.x * blockDim.x + threadIdx.x;
    if (i >= R * C) return;
    int r = i / C, c = i % C;
    out[(size_t)c * R + r] = f2bf(in[i]);
}

// ---------------- GEMM1 (m97-style): x[M,512] @ w1t[256,512]^T -> fp8 h1 ----------------
// BM=128, BN=128, BK=64, 4 waves (2x2, each 64x64). LDS rows 128B, XOR-swizzled
// byte ^= (row&7)<<4. B staged via global_load_lds w/ pre-swizzled source;
// A reg-staged (f32 load -> cvt_pk_bf16 -> swizzled ds_write_b128).
__global__ __launch_bounds__(256) void k_gemm1(const float* __restrict__ x,
                                               const ushort* __restrict__ w1t,
                                               uchar* __restrict__ h1f8, int M, int K) {
    constexpr int BM = 128, BN = 128, BK = 64;
    __shared__ __align__(16) ushort As[BM * BK];
    __shared__ __align__(16) ushort Bs[BN * BK];

    int t = threadIdx.x;
    int w = t >> 6, l = t & 63;
    int wm = w & 1, wn = w >> 1;
    int bm = blockIdx.x * BM, bn = blockIdx.y * BN;
    int lr = l & 15, g4 = l >> 4;

    f32x4 acc[4][4] = {};

    // A staging: thread t -> row ar=t>>1, 64B half (t&1); 4x b128 writes
    int ar = t >> 1;
    int ah = t & 1;
    int arow_g = bm + ar;
    bool aok = arow_g < M;
    const float* ap = x + (size_t)arow_g * K + ah * 32;
    char* adst = (char*)As + ar * 128;
    int aswz = (ar & 7) << 4;

    // B staging: wave w issue i: rows bn + w*32 + i*8 + (l>>3), seg (l&7)*16
    int brow_loc = (l >> 3);          // 0..7 within issue
    int bseg = ((l & 7) << 4) ^ (brow_loc << 4);  // pre-swizzled source byte in row

    for (int k0 = 0; k0 < K; k0 += BK) {
        // ---- issue B tile: 16 x global_load_lds (4 per wave) ----
#pragma unroll
        for (int i = 0; i < 4; ++i) {
            int rbase = w * 32 + i * 8;
            const char* gsrc = (const char*)w1t + (size_t)(bn + rbase + brow_loc) * (K * 2) + k0 * 2 + bseg;
            __builtin_amdgcn_global_load_lds(
                (const __attribute__((address_space(1))) uint*)gsrc,
                (__attribute__((address_space(3))) uint*)((char*)Bs + rbase * 128),
                16, 0, 0);
        }
        // ---- A tile: 8 float4 loads -> 16 cvt_pk -> 4 swizzled b128 writes ----
        {
            float4 f[8];
#pragma unroll
            for (int j = 0; j < 8; ++j)
                f[j] = aok ? *(const float4*)(ap + k0 + j * 4) : make_float4(0.f, 0.f, 0.f, 0.f);
#pragma unroll
            for (int j = 0; j < 4; ++j) {
                uint p0 = cvtpk_bf16(f[2 * j].x, f[2 * j].y);
                uint p1 = cvtpk_bf16(f[2 * j].z, f[2 * j].w);
                uint p2 = cvtpk_bf16(f[2 * j + 1].x, f[2 * j + 1].y);
                uint p3 = cvtpk_bf16(f[2 * j + 1].z, f[2 * j + 1].w);
                int4 v = make_int4((int)p0, (int)p1, (int)p2, (int)p3);
                *(int4*)(adst + ((ah * 64 + j * 16) ^ aswz)) = v;
            }
        }
        __syncthreads();
        // ---- compute: 2 ksub x 16 MFMA ----
#pragma unroll
        for (int ks = 0; ks < 2; ++ks) {
            short8 af[4], bfr[4];
#pragma unroll
            for (int mt = 0; mt < 4; ++mt) {
                int r = wm * 64 + mt * 16 + lr;
                af[mt] = *(const short8*)((const char*)As + r * 128 + ((ks * 64 + g4 * 16) ^ ((r & 7) << 4)));
            }
#pragma unroll
            for (int nt = 0; nt < 4; ++nt) {
                int r = wn * 64 + nt * 16 + lr;
                bfr[nt] = *(const short8*)((const char*)Bs + r * 128 + ((ks * 64 + g4 * 16) ^ ((r & 7) << 4)));
            }
#pragma unroll
            for (int mt = 0; mt < 4; ++mt)
#pragma unroll
                for (int nt = 0; nt < 4; ++nt)
                    acc[mt][nt] = __builtin_amdgcn_mfma_f32_16x16x32_bf16(af[mt], bfr[nt], acc[mt][nt], 0, 0, 0);
        }
        __syncthreads();
    }

#pragma unroll
    for (int mt = 0; mt < 4; ++mt)
#pragma unroll
        for (int nt = 0; nt < 4; ++nt)
#pragma unroll
            for (int i = 0; i < 4; ++i) {
                int row = bm + wm * 64 + mt * 16 + g4 * 4 + i;
                int col = bn + wn * 64 + nt * 16 + lr;
                if (row < M) h1f8[(size_t)row * 256 + col] = f2fp8(acc[mt][nt][i]);
            }
}

// ---------------- GEMM2: h1a[M,256] @ W2t[64,256]^T -> bf16 h2 ----------------
__global__ __launch_bounds__(256) void k_gemm2(const ushort* __restrict__ A,
                                               const ushort* __restrict__ Bt,
                                               ushort* __restrict__ Cb,
                                               int M, int K) {
    constexpr int BM = 64, BN = 64;
    constexpr int NT = 4;
    constexpr int SA = 40;
    __shared__ ushort As[BM * SA];
    __shared__ ushort Bs[BN * SA];

    int t = threadIdx.x;
    int w = t >> 6, l = t & 63;
    int bm = blockIdx.x * BM;
    int lr = l & 15, lk = (l >> 4) * 8;

    f32x4 acc[NT] = {};
    const int ACH = BM * 4;
    const int BCH = BN * 4;

    for (int k0 = 0; k0 < K; k0 += 32) {
        for (int c = t; c < ACH + BCH; c += 256) {
            if (c < ACH) {
                int row = c >> 2, seg = c & 3;
                int gr = bm + row;
                int4 v = make_int4(0, 0, 0, 0);
                if (gr < M) v = *(const int4*)(A + (size_t)gr * K + k0 + seg * 8);
                *(int4*)(&As[row * SA + seg * 8]) = v;
            } else {
                int cc = c - ACH;
                int row = cc >> 2, seg = cc & 3;
                int4 v = *(const int4*)(Bt + (size_t)row * K + k0 + seg * 8);
                *(int4*)(&Bs[row * SA + seg * 8]) = v;
            }
        }
        __syncthreads();
        short8 af = *(const short8*)(&As[(w * 16 + lr) * SA + lk]);
        short8 bfr[NT];
#pragma unroll
        for (int nt = 0; nt < NT; ++nt)
            bfr[nt] = *(const short8*)(&Bs[(nt * 16 + lr) * SA + lk]);
#pragma unroll
        for (int nt = 0; nt < NT; ++nt)
            acc[nt] = __builtin_amdgcn_mfma_f32_16x16x32_bf16(af, bfr[nt], acc[nt], 0, 0, 0);
        __syncthreads();
    }

#pragma unroll
    for (int nt = 0; nt < NT; ++nt)
#pragma unroll
        for (int i = 0; i < 4; ++i) {
            int row = bm + w * 16 + (l >> 4) * 4 + i;
            int col = nt * 16 + lr;
            if (row < M) Cb[(size_t)row * BN + col] = f2bf(acc[nt][i]);
        }
}

// ---------------- layer-1 aggregation + bias + relu (fp8 in / bf16 out) ----------------
__global__ __launch_bounds__(256) void k_agg1(const uchar* __restrict__ h8,
                                              const int* __restrict__ rowstart,
                                              const int* __restrict__ esrc,
                                              const float* __restrict__ ew,
                                              const float* __restrict__ dinv,
                                              const float* __restrict__ b1,
                                              ushort* __restrict__ out) {
    int wave = threadIdx.x >> 6;
    int lane = threadIdx.x & 63;
    int n = blockIdx.x * 4 + wave;
    if (n >= NODES) return;
    float4 acc = make_float4(0.f, 0.f, 0.f, 0.f);
    int e0 = rowstart[n], e1 = rowstart[n + 1];
    int e = e0;
#define A1_STEP(wt, qv)                                                       \
    {                                                                         \
        f32x2 lo = __builtin_amdgcn_cvt_pk_f32_fp8((int)(qv), false);         \
        f32x2 hi = __builtin_amdgcn_cvt_pk_f32_fp8((int)(qv), true);          \
        acc.x = fmaf(wt, lo[0], acc.x);                                       \
        acc.y = fmaf(wt, lo[1], acc.y);                                       \
        acc.z = fmaf(wt, hi[0], acc.z);                                       \
        acc.w = fmaf(wt, hi[1], acc.w);                                       \
    }
    for (; e + 8 <= e1; e += 8) {
        int s0 = esrc[e],     s1 = esrc[e + 1], s2 = esrc[e + 2], s3 = esrc[e + 3];
        int s4 = esrc[e + 4], s5 = esrc[e + 5], s6 = esrc[e + 6], s7 = esrc[e + 7];
        float w0 = ew[e],     w1 = ew[e + 1], w2 = ew[e + 2], w3 = ew[e + 3];
        float w4 = ew[e + 4], w5 = ew[e + 5], w6 = ew[e + 6], w7 = ew[e + 7];
        uint v0 = *(const uint*)(h8 + (size_t)s0 * 256 + lane * 4);
        uint v1 = *(const uint*)(h8 + (size_t)s1 * 256 + lane * 4);
        uint v2 = *(const uint*)(h8 + (size_t)s2 * 256 + lane * 4);
        uint v3 = *(const uint*)(h8 + (size_t)s3 * 256 + lane * 4);
        uint v4 = *(const uint*)(h8 + (size_t)s4 * 256 + lane * 4);
        uint v5 = *(const uint*)(h8 + (size_t)s5 * 256 + lane * 4);
        uint v6 = *(const uint*)(h8 + (size_t)s6 * 256 + lane * 4);
        uint v7 = *(const uint*)(h8 + (size_t)s7 * 256 + lane * 4);
        A1_STEP(w0, v0) A1_STEP(w1, v1) A1_STEP(w2, v2) A1_STEP(w3, v3)
        A1_STEP(w4, v4) A1_STEP(w5, v5) A1_STEP(w6, v6) A1_STEP(w7, v7)
    }
    for (; e < e1; ++e) {
        int s = esrc[e];
        float wt = ew[e];
        uint v = *(const uint*)(h8 + (size_t)s * 256 + lane * 4);
        A1_STEP(wt, v)
    }
#undef A1_STEP
    float dn = dinv[n];
    float s2v = dn * dn;
    uint qs = *(const uint*)(h8 + (size_t)n * 256 + lane * 4);
    f32x2 slo = __builtin_amdgcn_cvt_pk_f32_fp8((int)qs, false);
    f32x2 shi = __builtin_amdgcn_cvt_pk_f32_fp8((int)qs, true);
    float4 bb = *(const float4*)(b1 + lane * 4);
    ushort4 r;
    r.x = f2bf(fmaxf(fmaf(acc.x, dn, fmaf(slo[0], s2v, bb.x)), 0.f));
    r.y = f2bf(fmaxf(fmaf(acc.y, dn, fmaf(slo[1], s2v, bb.y)), 0.f));
    r.z = f2bf(fmaxf(fmaf(acc.z, dn, fmaf(shi[0], s2v, bb.z)), 0.f));
    r.w = f2bf(fmaxf(fmaf(acc.w, dn, fmaf(shi[1], s2v, bb.w)), 0.f));
    *(ushort4*)(out + (size_t)n * 256 + lane * 4) = r;
}

// ---------------- layer-2 aggregation + bias + log_softmax (bf16 h2) ----------------
__global__ __launch_bounds__(256) void k_agg2(const ushort* __restrict__ h,
                                              const int* __restrict__ rowstart,
                                              const int* __restrict__ esrc,
                                              const float* __restrict__ ew,
                                              const float* __restrict__ dinv,
                                              const float* __restrict__ b2,
                                              float* __restrict__ out) {
    int wave = threadIdx.x >> 6;
    int lane = threadIdx.x & 63;
    int n = blockIdx.x * 4 + wave;
    if (n >= NODES) return;
    float acc = 0.f;
    int e0 = rowstart[n], e1 = rowstart[n + 1];
    int e = e0;
    for (; e + 8 <= e1; e += 8) {
        int s0 = esrc[e],     s1 = esrc[e + 1], s2 = esrc[e + 2], s3 = esrc[e + 3];
        int s4 = esrc[e + 4], s5 = esrc[e + 5], s6 = esrc[e + 6], s7 = esrc[e + 7];
        float w0 = ew[e],     w1 = ew[e + 1], w2 = ew[e + 2], w3 = ew[e + 3];
        float w4 = ew[e + 4], w5 = ew[e + 5], w6 = ew[e + 6], w7 = ew[e + 7];
        float v0 = bf2f(h[(size_t)s0 * 64 + lane]);
        float v1 = bf2f(h[(size_t)s1 * 64 + lane]);
        float v2 = bf2f(h[(size_t)s2 * 64 + lane]);
        float v3 = bf2f(h[(size_t)s3 * 64 + lane]);
        float v4 = bf2f(h[(size_t)s4 * 64 + lane]);
        float v5 = bf2f(h[(size_t)s5 * 64 + lane]);
        float v6 = bf2f(h[(size_t)s6 * 64 + lane]);
        float v7 = bf2f(h[(size_t)s7 * 64 + lane]);
        acc = fmaf(w0, v0, acc); acc = fmaf(w1, v1, acc);
        acc = fmaf(w2, v2, acc); acc = fmaf(w3, v3, acc);
        acc = fmaf(w4, v4, acc); acc = fmaf(w5, v5, acc);
        acc = fmaf(w6, v6, acc); acc = fmaf(w7, v7, acc);
    }
    for (; e < e1; ++e)
        acc = fmaf(ew[e], bf2f(h[(size_t)esrc[e] * 64 + lane]), acc);
    float dn = dinv[n];
    float r = fmaf(acc, dn, fmaf(bf2f(h[(size_t)n * 64 + lane]), dn * dn, b2[lane]));
    float m = r;
#pragma unroll
    for (int off = 32; off; off >>= 1) m = fmaxf(m, __shfl_xor(m, off));
    float ex = __expf(r - m);
    float ssum = ex;
#pragma unroll
    for (int off = 32; off; off >>= 1) ssum += __shfl_xor(ssum, off);
    out[(size_t)n * 64 + lane] = r - m - __logf(ssum);
}

// ---------------- launch ----------------

extern "C" void kernel_launch(void* const* d_in, const int* in_sizes, int n_in,
                              void* d_out, int out_size, void* d_ws, size_t ws_size,
                              hipStream_t stream) {
    const float* x  = (const float*)d_in[0];
    const float* W1 = (const float*)d_in[1];
    const float* b1 = (const float*)d_in[2];
    const float* W2 = (const float*)d_in[3];
    const float* b2 = (const float*)d_in[4];
    const int*   ei = (const int*)d_in[5];
    int E = in_sizes[5] / 2;
    const int* src = ei;
    const int* dst = ei + E;
    float* out = (float*)d_out;

    int nblk = (E + EPB - 1) / EPB;   // 782

    char* wsp = (char*)d_ws;
    auto alloc = [&](size_t bytes) {
        char* p = wsp;
        wsp += (bytes + 255) & ~(size_t)255;
        return p;
    };
    int*    hist     = (int*)alloc((size_t)NBIN * nblk * 4);
    int*    offl     = (int*)alloc((size_t)NBIN * nblk * 4);
    int*    btot     = (int*)alloc((size_t)NBIN * 4);
    int*    binoff   = (int*)alloc((size_t)(NBIN + 1) * 4);
    int*    rowstart = (int*)alloc((size_t)(NODES + 1) * 4);
    float*  dinv     = (float*)alloc((size_t)NODES * 4);
    int2*   tmp      = (int2*)alloc((size_t)E * 8);
    int*    esrc     = (int*)alloc((size_t)E * 4);
    float*  ew       = (float*)alloc((size_t)E * 4);
    ushort* w1t      = (ushort*)alloc((size_t)256 * 512 * 2);
    ushort* w2t      = (ushort*)alloc((size_t)64 * 256 * 2);
    uchar*  h1f8     = (uchar*)alloc((size_t)NODES * 256);
    ushort* h1ab     = (ushort*)alloc((size_t)NODES * 256 * 2);
    ushort* h2b      = (ushort*)alloc((size_t)NODES * 64 * 2);

    // ---- CSR build (no global atomics, dense writes) ----
    k_hist<<<nblk, 256, 0, stream>>>(dst, E, hist, nblk);
    k_scanbin<<<NBIN, 1024, 0, stream>>>(hist, offl, btot, nblk);
    k_scanoff<<<1, 256, 0, stream>>>(btot, binoff, rowstart, E);
    k_part<<<nblk, 256, 0, stream>>>(src, dst, E, offl, binoff, nblk, tmp);
    k_csr<<<NBIN, 256, 0, stream>>>(tmp, binoff, rowstart, dinv, esrc);
    k_wfill<<<(E + 255) / 256, 256, 0, stream>>>(esrc, dinv, ew, E);

    // ---- weight casts ----
    k_castT<<<(512 * 256 + 255) / 256, 256, 0, stream>>>(W1, w1t, 512, 256);
    k_castT<<<(256 * 64 + 255) / 256, 256, 0, stream>>>(W2, w2t, 256, 64);

    // ---- layer 1 ----
    k_gemm1<<<dim3((NODES + 127) / 128, 2), 256, 0, stream>>>(x, w1t, h1f8, NODES, 512);
    k_agg1<<<(NODES + 3) / 4, 256, 0, stream>>>(h1f8, rowstart, esrc, ew, dinv, b1, h1ab);

    // ---- layer 2 ----
    k_gemm2<<<(NODES + 63) / 64, 256, 0, stream>>>(h1ab, w2t, h2b, NODES, 256);
    k_agg2<<<(NODES + 3) / 4, 256, 0, stream>>>(h2b, rowstart, esrc, ew, dinv, b2, out);
}

// Round 11
// 226.261 us; speedup vs baseline: 3.3729x; 1.0935x over previous
//
#include <hip/hip_runtime.h>

#define NODES 50000
#define NBIN 196          // ceil(50000/256) dst-bins of 256 nodes
#define EPB 2048          // edges per partition block

typedef __attribute__((ext_vector_type(8))) short short8;
typedef __attribute__((ext_vector_type(4))) float f32x4;
typedef __attribute__((ext_vector_type(2))) float f32x2;

__device__ __forceinline__ ushort f2bf(float f) {
    uint u = __float_as_uint(f);
    uint r = (u + 0x7fffu + ((u >> 16) & 1u)) >> 16;
    return (ushort)r;
}
__device__ __forceinline__ float bf2f(ushort u) {
    return __uint_as_float(((uint)u) << 16);
}
__device__ __forceinline__ uchar f2fp8(float f) {
    return (uchar)(__builtin_amdgcn_cvt_pk_fp8_f32(f, f, 0, false) & 0xff);
}
// HW packed f32x2 -> bf16x2 (RNE), one VALU op
__device__ __forceinline__ uint cvtpk_bf16(float lo, float hi) {
    uint r;
    asm("v_cvt_pk_bf16_f32 %0, %1, %2" : "=v"(r) : "v"(lo), "v"(hi));
    return r;
}

// ---------------- atomic-free two-level CSR build ----------------

__global__ __launch_bounds__(256) void k_hist(const int* __restrict__ dst, int E,
                                              int* __restrict__ hist, int nblk) {
    __shared__ int h[NBIN];
    int t = threadIdx.x;
    for (int i = t; i < NBIN; i += 256) h[i] = 0;
    __syncthreads();
    int base = blockIdx.x * EPB;
#pragma unroll
    for (int i = 0; i < EPB / 256; ++i) {
        int e = base + i * 256 + t;
        if (e < E) atomicAdd(&h[dst[e] >> 8], 1);
    }
    __syncthreads();
    for (int i = t; i < NBIN; i += 256) hist[i * nblk + blockIdx.x] = h[i];
}

__global__ __launch_bounds__(1024) void k_scanbin(const int* __restrict__ hist,
                                                  int* __restrict__ offl,
                                                  int* __restrict__ btot, int nblk) {
    __shared__ int s[1024];
    int b = blockIdx.x, t = threadIdx.x;
    int v = (t < nblk) ? hist[b * nblk + t] : 0;
    s[t] = v;
    __syncthreads();
    for (int off = 1; off < 1024; off <<= 1) {
        int u = (t >= off) ? s[t - off] : 0;
        __syncthreads();
        s[t] += u;
        __syncthreads();
    }
    if (t < nblk) offl[b * nblk + t] = s[t] - v;
    if (t == 1023) btot[b] = s[1023];
}

__global__ __launch_bounds__(256) void k_scanoff(const int* __restrict__ btot,
                                                 int* __restrict__ binoff,
                                                 int* __restrict__ rowstart, int E) {
    __shared__ int s[256];
    int t = threadIdx.x;
    int v = (t < NBIN) ? btot[t] : 0;
    s[t] = v;
    __syncthreads();
    for (int off = 1; off < 256; off <<= 1) {
        int u = (t >= off) ? s[t - off] : 0;
        __syncthreads();
        s[t] += u;
        __syncthreads();
    }
    if (t < NBIN) binoff[t] = s[t] - v;
    if (t == 0) { binoff[NBIN] = E; rowstart[NODES] = E; }
}

__global__ __launch_bounds__(256) void k_part(const int* __restrict__ src,
                                              const int* __restrict__ dst, int E,
                                              const int* __restrict__ offl,
                                              const int* __restrict__ binoff, int nblk,
                                              int2* __restrict__ tmp) {
    __shared__ int cur[NBIN];
    int t = threadIdx.x, blk = blockIdx.x;
    for (int i = t; i < NBIN; i += 256) cur[i] = binoff[i] + offl[i * nblk + blk];
    __syncthreads();
    int base = blk * EPB;
#pragma unroll
    for (int i = 0; i < EPB / 256; ++i) {
        int e = base + i * 256 + t;
        if (e < E) {
            int d = dst[e];
            int p = atomicAdd(&cur[d >> 8], 1);
            tmp[p] = make_int2(src[e], d);
        }
    }
}

__global__ __launch_bounds__(256) void k_csr(const int2* __restrict__ tmp,
                                             const int* __restrict__ binoff,
                                             int* __restrict__ rowstart,
                                             float* __restrict__ dinv,
                                             int* __restrict__ esrc) {
    __shared__ int ncnt[256], nst[256];
    int b = blockIdx.x, t = threadIdx.x;
    int e0 = binoff[b], e1 = binoff[b + 1];
    int nb0 = b << 8;
    int nn = min(256, NODES - nb0);
    ncnt[t] = 0;
    __syncthreads();
    for (int e = e0 + t; e < e1; e += 256) atomicAdd(&ncnt[tmp[e].y - nb0], 1);
    __syncthreads();
    int v = ncnt[t];
    nst[t] = v;
    __syncthreads();
    for (int off = 1; off < 256; off <<= 1) {
        int u = (t >= off) ? nst[t - off] : 0;
        __syncthreads();
        nst[t] += u;
        __syncthreads();
    }
    int excl = nst[t] - v;
    if (t < nn) {
        rowstart[nb0 + t] = e0 + excl;
        dinv[nb0 + t] = rsqrtf(1.0f + (float)v);
    }
    __syncthreads();
    ncnt[t] = e0 + excl;
    __syncthreads();
    for (int e = e0 + t; e < e1; e += 256) {
        int2 q = tmp[e];
        int p = atomicAdd(&ncnt[q.y - nb0], 1);
        esrc[p] = q.x;
    }
}

__global__ void k_wfill(const int* __restrict__ esrc, const float* __restrict__ dinv,
                        float* __restrict__ ew, int E) {
    int e = blockIdx.x * blockDim.x + threadIdx.x;
    if (e < E) ew[e] = dinv[esrc[e]];
}

// ---------------- casts ----------------

__global__ void k_castT(const float* __restrict__ in, ushort* __restrict__ out, int R, int C) {
    int i = blockIdx.x * blockDim.x + threadIdx.x;
    if (i >= R * C) return;
    int r = i / C, c = i % C;
    out[(size_t)c * R + r] = f2bf(in[i]);
}

// ---------------- GEMM1: x[M,512] @ w1t[256,512]^T -> fp8 h1 ----------------
// BM=64 (grid 1564 -> ~6 blocks/CU, 24 waves/CU), BN=128, BK=64.
// 4 waves 2x2, wave tile 32x64. LDS rows 128B XOR-swizzled (row&7)<<4.
// B via global_load_lds w/ pre-swizzled source; A reg-staged f32->bf16.
__global__ __launch_bounds__(256) void k_gemm1(const float* __restrict__ x,
                                               const ushort* __restrict__ w1t,
                                               uchar* __restrict__ h1f8, int M, int K) {
    constexpr int BM = 64, BN = 128, BK = 64;
    __shared__ __align__(16) ushort As[BM * BK];   // 8 KB
    __shared__ __align__(16) ushort Bs[BN * BK];   // 16 KB

    int t = threadIdx.x;
    int w = t >> 6, l = t & 63;
    int wm = w & 1, wn = w >> 1;
    int bm = blockIdx.x * BM, bn = blockIdx.y * BN;
    int lr = l & 15, g4 = l >> 4;

    f32x4 acc[2][4] = {};

    // A staging: thread t -> row t>>2 (0..63), quarter q=t&3 (32B of bf16 out of 128B row)
    int ar = t >> 2;
    int aq = t & 3;
    int arow_g = bm + ar;
    bool aok = arow_g < M;
    const float* ap = x + (size_t)arow_g * K + aq * 16;
    char* adst = (char*)As + ar * 128;
    int aswz = (ar & 7) << 4;

    // B staging: wave w, issue i: row = w*32 + i*8 + (l>>3); src byte pre-swizzled
    int brow_loc = l >> 3;                         // 0..7
    int bseg = ((l & 7) << 4) ^ (brow_loc << 4);   // pre-swizzled byte-in-row

    for (int k0 = 0; k0 < K; k0 += BK) {
        // ---- issue B tile: 16 x global_load_lds (4 per wave) ----
#pragma unroll
        for (int i = 0; i < 4; ++i) {
            int rbase = w * 32 + i * 8;
            const char* gsrc = (const char*)w1t + (size_t)(bn + rbase + brow_loc) * (K * 2) + k0 * 2 + bseg;
            __builtin_amdgcn_global_load_lds(
                (const __attribute__((address_space(1))) uint*)gsrc,
                (__attribute__((address_space(3))) uint*)((char*)Bs + rbase * 128),
                16, 0, 0);
        }
        // ---- A tile: 4 float4 loads -> 8 cvt_pk -> 2 swizzled b128 writes ----
        {
            float4 f[4];
#pragma unroll
            for (int j = 0; j < 4; ++j)
                f[j] = aok ? *(const float4*)(ap + k0 + j * 4) : make_float4(0.f, 0.f, 0.f, 0.f);
#pragma unroll
            for (int j = 0; j < 2; ++j) {
                uint p0 = cvtpk_bf16(f[2 * j].x, f[2 * j].y);
                uint p1 = cvtpk_bf16(f[2 * j].z, f[2 * j].w);
                uint p2 = cvtpk_bf16(f[2 * j + 1].x, f[2 * j + 1].y);
                uint p3 = cvtpk_bf16(f[2 * j + 1].z, f[2 * j + 1].w);
                int4 v = make_int4((int)p0, (int)p1, (int)p2, (int)p3);
                *(int4*)(adst + ((aq * 32 + j * 16) ^ aswz)) = v;
            }
        }
        __syncthreads();
        // ---- compute: 2 ksub x 8 MFMA ----
#pragma unroll
        for (int ks = 0; ks < 2; ++ks) {
            short8 af[2], bfr[4];
#pragma unroll
            for (int mt = 0; mt < 2; ++mt) {
                int r = wm * 32 + mt * 16 + lr;
                af[mt] = *(const short8*)((const char*)As + r * 128 + ((ks * 64 + g4 * 16) ^ ((r & 7) << 4)));
            }
#pragma unroll
            for (int nt = 0; nt < 4; ++nt) {
                int r = wn * 64 + nt * 16 + lr;
                bfr[nt] = *(const short8*)((const char*)Bs + r * 128 + ((ks * 64 + g4 * 16) ^ ((r & 7) << 4)));
            }
#pragma unroll
            for (int mt = 0; mt < 2; ++mt)
#pragma unroll
                for (int nt = 0; nt < 4; ++nt)
                    acc[mt][nt] = __builtin_amdgcn_mfma_f32_16x16x32_bf16(af[mt], bfr[nt], acc[mt][nt], 0, 0, 0);
        }
        __syncthreads();
    }

#pragma unroll
    for (int mt = 0; mt < 2; ++mt)
#pragma unroll
        for (int nt = 0; nt < 4; ++nt)
#pragma unroll
            for (int i = 0; i < 4; ++i) {
                int row = bm + wm * 32 + mt * 16 + g4 * 4 + i;
                int col = bn + wn * 64 + nt * 16 + lr;
                if (row < M) h1f8[(size_t)row * 256 + col] = f2fp8(acc[mt][nt][i]);
            }
}

// ---------------- GEMM2: h1a[M,256] @ W2t[64,256]^T -> bf16 h2 ----------------
__global__ __launch_bounds__(256) void k_gemm2(const ushort* __restrict__ A,
                                               const ushort* __restrict__ Bt,
                                               ushort* __restrict__ Cb,
                                               int M, int K) {
    constexpr int BM = 64, BN = 64;
    constexpr int NT = 4;
    constexpr int SA = 40;
    __shared__ ushort As[BM * SA];
    __shared__ ushort Bs[BN * SA];

    int t = threadIdx.x;
    int w = t >> 6, l = t & 63;
    int bm = blockIdx.x * BM;
    int lr = l & 15, lk = (l >> 4) * 8;

    f32x4 acc[NT] = {};
    const int ACH = BM * 4;
    const int BCH = BN * 4;

    for (int k0 = 0; k0 < K; k0 += 32) {
        for (int c = t; c < ACH + BCH; c += 256) {
            if (c < ACH) {
                int row = c >> 2, seg = c & 3;
                int gr = bm + row;
                int4 v = make_int4(0, 0, 0, 0);
                if (gr < M) v = *(const int4*)(A + (size_t)gr * K + k0 + seg * 8);
                *(int4*)(&As[row * SA + seg * 8]) = v;
            } else {
                int cc = c - ACH;
                int row = cc >> 2, seg = cc & 3;
                int4 v = *(const int4*)(Bt + (size_t)row * K + k0 + seg * 8);
                *(int4*)(&Bs[row * SA + seg * 8]) = v;
            }
        }
        __syncthreads();
        short8 af = *(const short8*)(&As[(w * 16 + lr) * SA + lk]);
        short8 bfr[NT];
#pragma unroll
        for (int nt = 0; nt < NT; ++nt)
            bfr[nt] = *(const short8*)(&Bs[(nt * 16 + lr) * SA + lk]);
#pragma unroll
        for (int nt = 0; nt < NT; ++nt)
            acc[nt] = __builtin_amdgcn_mfma_f32_16x16x32_bf16(af, bfr[nt], acc[nt], 0, 0, 0);
        __syncthreads();
    }

#pragma unroll
    for (int nt = 0; nt < NT; ++nt)
#pragma unroll
        for (int i = 0; i < 4; ++i) {
            int row = bm + w * 16 + (l >> 4) * 4 + i;
            int col = nt * 16 + lr;
            if (row < M) Cb[(size_t)row * BN + col] = f2bf(acc[nt][i]);
        }
}

// ---------------- layer-1 aggregation + bias + relu (fp8 in / bf16 out) ----------------
__global__ __launch_bounds__(256) void k_agg1(const uchar* __restrict__ h8,
                                              const int* __restrict__ rowstart,
                                              const int* __restrict__ esrc,
                                              const float* __restrict__ ew,
                                              const float* __restrict__ dinv,
                                              const float* __restrict__ b1,
                                              ushort* __restrict__ out) {
    int wave = threadIdx.x >> 6;
    int lane = threadIdx.x & 63;
    int n = blockIdx.x * 4 + wave;
    if (n >= NODES) return;
    float4 acc = make_float4(0.f, 0.f, 0.f, 0.f);
    int e0 = rowstart[n], e1 = rowstart[n + 1];
    int e = e0;
#define A1_STEP(wt, qv)                                                       \
    {                                                                         \
        f32x2 lo = __builtin_amdgcn_cvt_pk_f32_fp8((int)(qv), false);         \
        f32x2 hi = __builtin_amdgcn_cvt_pk_f32_fp8((int)(qv), true);          \
        acc.x = fmaf(wt, lo[0], acc.x);                                       \
        acc.y = fmaf(wt, lo[1], acc.y);                                       \
        acc.z = fmaf(wt, hi[0], acc.z);                                       \
        acc.w = fmaf(wt, hi[1], acc.w);                                       \
    }
    for (; e + 8 <= e1; e += 8) {
        int s0 = esrc[e],     s1 = esrc[e + 1], s2 = esrc[e + 2], s3 = esrc[e + 3];
        int s4 = esrc[e + 4], s5 = esrc[e + 5], s6 = esrc[e + 6], s7 = esrc[e + 7];
        float w0 = ew[e],     w1 = ew[e + 1], w2 = ew[e + 2], w3 = ew[e + 3];
        float w4 = ew[e + 4], w5 = ew[e + 5], w6 = ew[e + 6], w7 = ew[e + 7];
        uint v0 = *(const uint*)(h8 + (size_t)s0 * 256 + lane * 4);
        uint v1 = *(const uint*)(h8 + (size_t)s1 * 256 + lane * 4);
        uint v2 = *(const uint*)(h8 + (size_t)s2 * 256 + lane * 4);
        uint v3 = *(const uint*)(h8 + (size_t)s3 * 256 + lane * 4);
        uint v4 = *(const uint*)(h8 + (size_t)s4 * 256 + lane * 4);
        uint v5 = *(const uint*)(h8 + (size_t)s5 * 256 + lane * 4);
        uint v6 = *(const uint*)(h8 + (size_t)s6 * 256 + lane * 4);
        uint v7 = *(const uint*)(h8 + (size_t)s7 * 256 + lane * 4);
        A1_STEP(w0, v0) A1_STEP(w1, v1) A1_STEP(w2, v2) A1_STEP(w3, v3)
        A1_STEP(w4, v4) A1_STEP(w5, v5) A1_STEP(w6, v6) A1_STEP(w7, v7)
    }
    for (; e < e1; ++e) {
        int s = esrc[e];
        float wt = ew[e];
        uint v = *(const uint*)(h8 + (size_t)s * 256 + lane * 4);
        A1_STEP(wt, v)
    }
#undef A1_STEP
    float dn = dinv[n];
    float s2v = dn * dn;
    uint qs = *(const uint*)(h8 + (size_t)n * 256 + lane * 4);
    f32x2 slo = __builtin_amdgcn_cvt_pk_f32_fp8((int)qs, false);
    f32x2 shi = __builtin_amdgcn_cvt_pk_f32_fp8((int)qs, true);
    float4 bb = *(const float4*)(b1 + lane * 4);
    ushort4 r;
    r.x = f2bf(fmaxf(fmaf(acc.x, dn, fmaf(slo[0], s2v, bb.x)), 0.f));
    r.y = f2bf(fmaxf(fmaf(acc.y, dn, fmaf(slo[1], s2v, bb.y)), 0.f));
    r.z = f2bf(fmaxf(fmaf(acc.z, dn, fmaf(shi[0], s2v, bb.z)), 0.f));
    r.w = f2bf(fmaxf(fmaf(acc.w, dn, fmaf(shi[1], s2v, bb.w)), 0.f));
    *(ushort4*)(out + (size_t)n * 256 + lane * 4) = r;
}

// ---------------- layer-2 aggregation + bias + log_softmax (bf16 h2) ----------------
__global__ __launch_bounds__(256) void k_agg2(const ushort* __restrict__ h,
                                              const int* __restrict__ rowstart,
                                              const int* __restrict__ esrc,
                                              const float* __restrict__ ew,
                                              const float* __restrict__ dinv,
                                              const float* __restrict__ b2,
                                              float* __restrict__ out) {
    int wave = threadIdx.x >> 6;
    int lane = threadIdx.x & 63;
    int n = blockIdx.x * 4 + wave;
    if (n >= NODES) return;
    float acc = 0.f;
    int e0 = rowstart[n], e1 = rowstart[n + 1];
    int e = e0;
    for (; e + 8 <= e1; e += 8) {
        int s0 = esrc[e],     s1 = esrc[e + 1], s2 = esrc[e + 2], s3 = esrc[e + 3];
        int s4 = esrc[e + 4], s5 = esrc[e + 5], s6 = esrc[e + 6], s7 = esrc[e + 7];
        float w0 = ew[e],     w1 = ew[e + 1], w2 = ew[e + 2], w3 = ew[e + 3];
        float w4 = ew[e + 4], w5 = ew[e + 5], w6 = ew[e + 6], w7 = ew[e + 7];
        float v0 = bf2f(h[(size_t)s0 * 64 + lane]);
        float v1 = bf2f(h[(size_t)s1 * 64 + lane]);
        float v2 = bf2f(h[(size_t)s2 * 64 + lane]);
        float v3 = bf2f(h[(size_t)s3 * 64 + lane]);
        float v4 = bf2f(h[(size_t)s4 * 64 + lane]);
        float v5 = bf2f(h[(size_t)s5 * 64 + lane]);
        float v6 = bf2f(h[(size_t)s6 * 64 + lane]);
        float v7 = bf2f(h[(size_t)s7 * 64 + lane]);
        acc = fmaf(w0, v0, acc); acc = fmaf(w1, v1, acc);
        acc = fmaf(w2, v2, acc); acc = fmaf(w3, v3, acc);
        acc = fmaf(w4, v4, acc); acc = fmaf(w5, v5, acc);
        acc = fmaf(w6, v6, acc); acc = fmaf(w7, v7, acc);
    }
    for (; e < e1; ++e)
        acc = fmaf(ew[e], bf2f(h[(size_t)esrc[e] * 64 + lane]), acc);
    float dn = dinv[n];
    float r = fmaf(acc, dn, fmaf(bf2f(h[(size_t)n * 64 + lane]), dn * dn, b2[lane]));
    float m = r;
#pragma unroll
    for (int off = 32; off; off >>= 1) m = fmaxf(m, __shfl_xor(m, off));
    float ex = __expf(r - m);
    float ssum = ex;
#pragma unroll
    for (int off = 32; off; off >>= 1) ssum += __shfl_xor(ssum, off);
    out[(size_t)n * 64 + lane] = r - m - __logf(ssum);
}

// ---------------- launch ----------------

extern "C" void kernel_launch(void* const* d_in, const int* in_sizes, int n_in,
                              void* d_out, int out_size, void* d_ws, size_t ws_size,
                              hipStream_t stream) {
    const float* x  = (const float*)d_in[0];
    const float* W1 = (const float*)d_in[1];
    const float* b1 = (const float*)d_in[2];
    const float* W2 = (const float*)d_in[3];
    const float* b2 = (const float*)d_in[4];
    const int*   ei = (const int*)d_in[5];
    int E = in_sizes[5] / 2;
    const int* src = ei;
    const int* dst = ei + E;
    float* out = (float*)d_out;

    int nblk = (E + EPB - 1) / EPB;   // 782

    char* wsp = (char*)d_ws;
    auto alloc = [&](size_t bytes) {
        char* p = wsp;
        wsp += (bytes + 255) & ~(size_t)255;
        return p;
    };
    int*    hist     = (int*)alloc((size_t)NBIN * nblk * 4);
    int*    offl     = (int*)alloc((size_t)NBIN * nblk * 4);
    int*    btot     = (int*)alloc((size_t)NBIN * 4);
    int*    binoff   = (int*)alloc((size_t)(NBIN + 1) * 4);
    int*    rowstart = (int*)alloc((size_t)(NODES + 1) * 4);
    float*  dinv     = (float*)alloc((size_t)NODES * 4);
    int2*   tmp      = (int2*)alloc((size_t)E * 8);
    int*    esrc     = (int*)alloc((size_t)E * 4);
    float*  ew       = (float*)alloc((size_t)E * 4);
    ushort* w1t      = (ushort*)alloc((size_t)256 * 512 * 2);
    ushort* w2t      = (ushort*)alloc((size_t)64 * 256 * 2);
    uchar*  h1f8     = (uchar*)alloc((size_t)NODES * 256);
    ushort* h1ab     = (ushort*)alloc((size_t)NODES * 256 * 2);
    ushort* h2b      = (ushort*)alloc((size_t)NODES * 64 * 2);

    // ---- CSR build (no global atomics, dense writes) ----
    k_hist<<<nblk, 256, 0, stream>>>(dst, E, hist, nblk);
    k_scanbin<<<NBIN, 1024, 0, stream>>>(hist, offl, btot, nblk);
    k_scanoff<<<1, 256, 0, stream>>>(btot, binoff, rowstart, E);
    k_part<<<nblk, 256, 0, stream>>>(src, dst, E, offl, binoff, nblk, tmp);
    k_csr<<<NBIN, 256, 0, stream>>>(tmp, binoff, rowstart, dinv, esrc);
    k_wfill<<<(E + 255) / 256, 256, 0, stream>>>(esrc, dinv, ew, E);

    // ---- weight casts ----
    k_castT<<<(512 * 256 + 255) / 256, 256, 0, stream>>>(W1, w1t, 512, 256);
    k_castT<<<(256 * 64 + 255) / 256, 256, 0, stream>>>(W2, w2t, 256, 64);

    // ---- layer 1 ----
    k_gemm1<<<dim3((NODES + 63) / 64, 2), 256, 0, stream>>>(x, w1t, h1f8, NODES, 512);
    k_agg1<<<(NODES + 3) / 4, 256, 0, stream>>>(h1f8, rowstart, esrc, ew, dinv, b1, h1ab);

    // ---- layer 2 ----
    k_gemm2<<<(NODES + 63) / 64, 256, 0, stream>>>(h1ab, w2t, h2b, NODES, 256);
    k_agg2<<<(NODES + 3) / 4, 256, 0, stream>>>(h2b, rowstart, esrc, ew, dinv, b2, out);
}

// Round 12
// 200.882 us; speedup vs baseline: 3.7990x; 1.1263x over previous
//
#include <hip/hip_runtime.h>

#define NODES 50000
#define NBIN 196          // ceil(50000/256) dst-bins of 256 nodes
#define EPB 2048          // edges per partition block

typedef __attribute__((ext_vector_type(8))) short short8;
typedef __attribute__((ext_vector_type(4))) float f32x4;
typedef __attribute__((ext_vector_type(2))) float f32x2;

__device__ __forceinline__ ushort f2bf(float f) {
    uint u = __float_as_uint(f);
    uint r = (u + 0x7fffu + ((u >> 16) & 1u)) >> 16;
    return (ushort)r;
}
__device__ __forceinline__ float bf2f(ushort u) {
    return __uint_as_float(((uint)u) << 16);
}
__device__ __forceinline__ uchar f2fp8(float f) {
    return (uchar)(__builtin_amdgcn_cvt_pk_fp8_f32(f, f, 0, false) & 0xff);
}
// HW packed f32x2 -> bf16x2 (RNE), one VALU op
__device__ __forceinline__ uint cvtpk_bf16(float lo, float hi) {
    uint r;
    asm("v_cvt_pk_bf16_f32 %0, %1, %2" : "=v"(r) : "v"(lo), "v"(hi));
    return r;
}

// ---------------- atomic-free two-level CSR build ----------------

__global__ __launch_bounds__(256) void k_hist(const int* __restrict__ dst, int E,
                                              int* __restrict__ hist, int nblk) {
    __shared__ int h[NBIN];
    int t = threadIdx.x;
    for (int i = t; i < NBIN; i += 256) h[i] = 0;
    __syncthreads();
    int base = blockIdx.x * EPB;
#pragma unroll
    for (int i = 0; i < EPB / 256; ++i) {
        int e = base + i * 256 + t;
        if (e < E) atomicAdd(&h[dst[e] >> 8], 1);
    }
    __syncthreads();
    for (int i = t; i < NBIN; i += 256) hist[i * nblk + blockIdx.x] = h[i];
}

__global__ __launch_bounds__(1024) void k_scanbin(const int* __restrict__ hist,
                                                  int* __restrict__ offl,
                                                  int* __restrict__ btot, int nblk) {
    __shared__ int s[1024];
    int b = blockIdx.x, t = threadIdx.x;
    int v = (t < nblk) ? hist[b * nblk + t] : 0;
    s[t] = v;
    __syncthreads();
    for (int off = 1; off < 1024; off <<= 1) {
        int u = (t >= off) ? s[t - off] : 0;
        __syncthreads();
        s[t] += u;
        __syncthreads();
    }
    if (t < nblk) offl[b * nblk + t] = s[t] - v;
    if (t == 1023) btot[b] = s[1023];
}

__global__ __launch_bounds__(256) void k_scanoff(const int* __restrict__ btot,
                                                 int* __restrict__ binoff,
                                                 int* __restrict__ rowstart, int E) {
    __shared__ int s[256];
    int t = threadIdx.x;
    int v = (t < NBIN) ? btot[t] : 0;
    s[t] = v;
    __syncthreads();
    for (int off = 1; off < 256; off <<= 1) {
        int u = (t >= off) ? s[t - off] : 0;
        __syncthreads();
        s[t] += u;
        __syncthreads();
    }
    if (t < NBIN) binoff[t] = s[t] - v;
    if (t == 0) { binoff[NBIN] = E; rowstart[NODES] = E; }
}

__global__ __launch_bounds__(256) void k_csr(const int2* __restrict__ tmp,
                                             const int* __restrict__ binoff,
                                             int* __restrict__ rowstart,
                                             float* __restrict__ dinv,
                                             int* __restrict__ esrc) {
    __shared__ int ncnt[256], nst[256];
    int b = blockIdx.x, t = threadIdx.x;
    int e0 = binoff[b], e1 = binoff[b + 1];
    int nb0 = b << 8;
    int nn = min(256, NODES - nb0);
    ncnt[t] = 0;
    __syncthreads();
    for (int e = e0 + t; e < e1; e += 256) atomicAdd(&ncnt[tmp[e].y - nb0], 1);
    __syncthreads();
    int v = ncnt[t];
    nst[t] = v;
    __syncthreads();
    for (int off = 1; off < 256; off <<= 1) {
        int u = (t >= off) ? nst[t - off] : 0;
        __syncthreads();
        nst[t] += u;
        __syncthreads();
    }
    int excl = nst[t] - v;
    if (t < nn) {
        rowstart[nb0 + t] = e0 + excl;
        dinv[nb0 + t] = rsqrtf(1.0f + (float)v);
    }
    __syncthreads();
    ncnt[t] = e0 + excl;
    __syncthreads();
    for (int e = e0 + t; e < e1; e += 256) {
        int2 q = tmp[e];
        int p = atomicAdd(&ncnt[q.y - nb0], 1);
        esrc[p] = q.x;
    }
}

__global__ void k_wfill(const int* __restrict__ esrc, const float* __restrict__ dinv,
                        float* __restrict__ ew, int E) {
    int e = blockIdx.x * blockDim.x + threadIdx.x;
    if (e < E) ew[e] = dinv[esrc[e]];
}

// ---------------- casts ----------------

__global__ void k_castT(const float* __restrict__ in, ushort* __restrict__ out, int R, int C) {
    int i = blockIdx.x * blockDim.x + threadIdx.x;
    if (i >= R * C) return;
    int r = i / C, c = i % C;
    out[(size_t)c * R + r] = f2bf(in[i]);
}

// ---------------- fused: GEMM1 (x@W1 -> fp8 h1) ∥ edge partition ----------------
// blocks [0, gemmBlocks): m97-style GEMM, BM=64, BN=128, BK=64, swizzled LDS.
// blocks [gemmBlocks, +nblk): k_part (bin-reserved scatter, LDS cursors only).
__global__ __launch_bounds__(256) void k_gemm1_part(
    const float* __restrict__ x, const ushort* __restrict__ w1t,
    uchar* __restrict__ h1f8, int M, int K,
    const int* __restrict__ src, const int* __restrict__ dst, int E,
    const int* __restrict__ offl, const int* __restrict__ binoff, int nblk,
    int2* __restrict__ tmp, int gemmBlocks) {
    constexpr int BM = 64, BN = 128, BK = 64;
    __shared__ __align__(16) ushort As[BM * BK];   // 8 KB
    __shared__ __align__(16) ushort Bs[BN * BK];   // 16 KB
    __shared__ int cur[NBIN];

    int t = threadIdx.x;

    if (blockIdx.x >= gemmBlocks) {
        // ---- partition path ----
        int blk = blockIdx.x - gemmBlocks;
        for (int i = t; i < NBIN; i += 256) cur[i] = binoff[i] + offl[i * nblk + blk];
        __syncthreads();
        int base = blk * EPB;
#pragma unroll
        for (int i = 0; i < EPB / 256; ++i) {
            int e = base + i * 256 + t;
            if (e < E) {
                int d = dst[e];
                int p = atomicAdd(&cur[d >> 8], 1);
                tmp[p] = make_int2(src[e], d);
            }
        }
        return;
    }

    // ---- GEMM path ----
    int w = t >> 6, l = t & 63;
    int wm = w & 1, wn = w >> 1;
    int bm = (blockIdx.x >> 1) * BM;       // adjacent blocks share A rows -> L2 reuse
    int bn = (blockIdx.x & 1) * BN;
    int lr = l & 15, g4 = l >> 4;

    f32x4 acc[2][4] = {};

    int ar = t >> 2;
    int aq = t & 3;
    int arow_g = bm + ar;
    bool aok = arow_g < M;
    const float* ap = x + (size_t)arow_g * K + aq * 16;
    char* adst = (char*)As + ar * 128;
    int aswz = (ar & 7) << 4;

    int brow_loc = l >> 3;
    int bseg = ((l & 7) << 4) ^ (brow_loc << 4);

    for (int k0 = 0; k0 < K; k0 += BK) {
#pragma unroll
        for (int i = 0; i < 4; ++i) {
            int rbase = w * 32 + i * 8;
            const char* gsrc = (const char*)w1t + (size_t)(bn + rbase + brow_loc) * (K * 2) + k0 * 2 + bseg;
            __builtin_amdgcn_global_load_lds(
                (const __attribute__((address_space(1))) uint*)gsrc,
                (__attribute__((address_space(3))) uint*)((char*)Bs + rbase * 128),
                16, 0, 0);
        }
        {
            float4 f[4];
#pragma unroll
            for (int j = 0; j < 4; ++j)
                f[j] = aok ? *(const float4*)(ap + k0 + j * 4) : make_float4(0.f, 0.f, 0.f, 0.f);
#pragma unroll
            for (int j = 0; j < 2; ++j) {
                uint p0 = cvtpk_bf16(f[2 * j].x, f[2 * j].y);
                uint p1 = cvtpk_bf16(f[2 * j].z, f[2 * j].w);
                uint p2 = cvtpk_bf16(f[2 * j + 1].x, f[2 * j + 1].y);
                uint p3 = cvtpk_bf16(f[2 * j + 1].z, f[2 * j + 1].w);
                int4 v = make_int4((int)p0, (int)p1, (int)p2, (int)p3);
                *(int4*)(adst + ((aq * 32 + j * 16) ^ aswz)) = v;
            }
        }
        __syncthreads();
#pragma unroll
        for (int ks = 0; ks < 2; ++ks) {
            short8 af[2], bfr[4];
#pragma unroll
            for (int mt = 0; mt < 2; ++mt) {
                int r = wm * 32 + mt * 16 + lr;
                af[mt] = *(const short8*)((const char*)As + r * 128 + ((ks * 64 + g4 * 16) ^ ((r & 7) << 4)));
            }
#pragma unroll
            for (int nt = 0; nt < 4; ++nt) {
                int r = wn * 64 + nt * 16 + lr;
                bfr[nt] = *(const short8*)((const char*)Bs + r * 128 + ((ks * 64 + g4 * 16) ^ ((r & 7) << 4)));
            }
#pragma unroll
            for (int mt = 0; mt < 2; ++mt)
#pragma unroll
                for (int nt = 0; nt < 4; ++nt)
                    acc[mt][nt] = __builtin_amdgcn_mfma_f32_16x16x32_bf16(af[mt], bfr[nt], acc[mt][nt], 0, 0, 0);
        }
        __syncthreads();
    }

#pragma unroll
    for (int mt = 0; mt < 2; ++mt)
#pragma unroll
        for (int nt = 0; nt < 4; ++nt)
#pragma unroll
            for (int i = 0; i < 4; ++i) {
                int row = bm + wm * 32 + mt * 16 + g4 * 4 + i;
                int col = bn + wn * 64 + nt * 16 + lr;
                if (row < M) h1f8[(size_t)row * 256 + col] = f2fp8(acc[mt][nt][i]);
            }
}

// ---------------- GEMM2: h1a[M,256] @ W2t[64,256]^T -> bf16 h2 ----------------
__global__ __launch_bounds__(256) void k_gemm2(const ushort* __restrict__ A,
                                               const ushort* __restrict__ Bt,
                                               ushort* __restrict__ Cb,
                                               int M, int K) {
    constexpr int BM = 64, BN = 64;
    constexpr int NT = 4;
    constexpr int SA = 40;
    __shared__ ushort As[BM * SA];
    __shared__ ushort Bs[BN * SA];

    int t = threadIdx.x;
    int w = t >> 6, l = t & 63;
    int bm = blockIdx.x * BM;
    int lr = l & 15, lk = (l >> 4) * 8;

    f32x4 acc[NT] = {};
    const int ACH = BM * 4;
    const int BCH = BN * 4;

    for (int k0 = 0; k0 < K; k0 += 32) {
        for (int c = t; c < ACH + BCH; c += 256) {
            if (c < ACH) {
                int row = c >> 2, seg = c & 3;
                int gr = bm + row;
                int4 v = make_int4(0, 0, 0, 0);
                if (gr < M) v = *(const int4*)(A + (size_t)gr * K + k0 + seg * 8);
                *(int4*)(&As[row * SA + seg * 8]) = v;
            } else {
                int cc = c - ACH;
                int row = cc >> 2, seg = cc & 3;
                int4 v = *(const int4*)(Bt + (size_t)row * K + k0 + seg * 8);
                *(int4*)(&Bs[row * SA + seg * 8]) = v;
            }
        }
        __syncthreads();
        short8 af = *(const short8*)(&As[(w * 16 + lr) * SA + lk]);
        short8 bfr[NT];
#pragma unroll
        for (int nt = 0; nt < NT; ++nt)
            bfr[nt] = *(const short8*)(&Bs[(nt * 16 + lr) * SA + lk]);
#pragma unroll
        for (int nt = 0; nt < NT; ++nt)
            acc[nt] = __builtin_amdgcn_mfma_f32_16x16x32_bf16(af, bfr[nt], acc[nt], 0, 0, 0);
        __syncthreads();
    }

#pragma unroll
    for (int nt = 0; nt < NT; ++nt)
#pragma unroll
        for (int i = 0; i < 4; ++i) {
            int row = bm + w * 16 + (l >> 4) * 4 + i;
            int col = nt * 16 + lr;
            if (row < M) Cb[(size_t)row * BN + col] = f2bf(acc[nt][i]);
        }
}

// ---------------- layer-1 aggregation + bias + relu (fp8 in / bf16 out) ----------------
// edge stream scalarized: n/e0/e1 wave-uniform -> esrc/ew via SMEM, gathers saddr-form
__global__ __launch_bounds__(256) void k_agg1(const uchar* __restrict__ h8,
                                              const int* __restrict__ rowstart,
                                              const int* __restrict__ esrc,
                                              const float* __restrict__ ew,
                                              const float* __restrict__ dinv,
                                              const float* __restrict__ b1,
                                              ushort* __restrict__ out) {
    int wave = __builtin_amdgcn_readfirstlane(threadIdx.x >> 6);
    int lane = threadIdx.x & 63;
    int n = blockIdx.x * 4 + wave;
    if (n >= NODES) return;
    const uchar* hl = h8 + lane * 4;   // per-lane base; row base is scalar
    float4 acc = make_float4(0.f, 0.f, 0.f, 0.f);
    int e0 = __builtin_amdgcn_readfirstlane(rowstart[n]);
    int e1 = __builtin_amdgcn_readfirstlane(rowstart[n + 1]);
    int e = e0;
#define A1_STEP(wt, qv)                                                       \
    {                                                                         \
        f32x2 lo = __builtin_amdgcn_cvt_pk_f32_fp8((int)(qv), false);         \
        f32x2 hi = __builtin_amdgcn_cvt_pk_f32_fp8((int)(qv), true);          \
        acc.x = fmaf(wt, lo[0], acc.x);                                       \
        acc.y = fmaf(wt, lo[1], acc.y);                                       \
        acc.z = fmaf(wt, hi[0], acc.z);                                       \
        acc.w = fmaf(wt, hi[1], acc.w);                                       \
    }
    for (; e + 8 <= e1; e += 8) {
        int s0 = esrc[e],     s1 = esrc[e + 1], s2 = esrc[e + 2], s3 = esrc[e + 3];
        int s4 = esrc[e + 4], s5 = esrc[e + 5], s6 = esrc[e + 6], s7 = esrc[e + 7];
        float w0 = ew[e],     w1 = ew[e + 1], w2 = ew[e + 2], w3 = ew[e + 3];
        float w4 = ew[e + 4], w5 = ew[e + 5], w6 = ew[e + 6], w7 = ew[e + 7];
        uint v0 = *(const uint*)(hl + (size_t)s0 * 256);
        uint v1 = *(const uint*)(hl + (size_t)s1 * 256);
        uint v2 = *(const uint*)(hl + (size_t)s2 * 256);
        uint v3 = *(const uint*)(hl + (size_t)s3 * 256);
        uint v4 = *(const uint*)(hl + (size_t)s4 * 256);
        uint v5 = *(const uint*)(hl + (size_t)s5 * 256);
        uint v6 = *(const uint*)(hl + (size_t)s6 * 256);
        uint v7 = *(const uint*)(hl + (size_t)s7 * 256);
        A1_STEP(w0, v0) A1_STEP(w1, v1) A1_STEP(w2, v2) A1_STEP(w3, v3)
        A1_STEP(w4, v4) A1_STEP(w5, v5) A1_STEP(w6, v6) A1_STEP(w7, v7)
    }
    for (; e < e1; ++e) {
        int s = esrc[e];
        float wt = ew[e];
        uint v = *(const uint*)(hl + (size_t)s * 256);
        A1_STEP(wt, v)
    }
#undef A1_STEP
    float dn = dinv[n];
    float s2v = dn * dn;
    uint qs = *(const uint*)(hl + (size_t)n * 256);
    f32x2 slo = __builtin_amdgcn_cvt_pk_f32_fp8((int)qs, false);
    f32x2 shi = __builtin_amdgcn_cvt_pk_f32_fp8((int)qs, true);
    float4 bb = *(const float4*)(b1 + lane * 4);
    ushort4 r;
    r.x = f2bf(fmaxf(fmaf(acc.x, dn, fmaf(slo[0], s2v, bb.x)), 0.f));
    r.y = f2bf(fmaxf(fmaf(acc.y, dn, fmaf(slo[1], s2v, bb.y)), 0.f));
    r.z = f2bf(fmaxf(fmaf(acc.z, dn, fmaf(shi[0], s2v, bb.z)), 0.f));
    r.w = f2bf(fmaxf(fmaf(acc.w, dn, fmaf(shi[1], s2v, bb.w)), 0.f));
    *(ushort4*)(out + (size_t)n * 256 + lane * 4) = r;
}

// ---------------- layer-2 aggregation + bias + log_softmax (bf16 h2) ----------------
__global__ __launch_bounds__(256) void k_agg2(const ushort* __restrict__ h,
                                              const int* __restrict__ rowstart,
                                              const int* __restrict__ esrc,
                                              const float* __restrict__ ew,
                                              const float* __restrict__ dinv,
                                              const float* __restrict__ b2,
                                              float* __restrict__ out) {
    int wave = __builtin_amdgcn_readfirstlane(threadIdx.x >> 6);
    int lane = threadIdx.x & 63;
    int n = blockIdx.x * 4 + wave;
    if (n >= NODES) return;
    const ushort* hl = h + lane;
    float acc = 0.f;
    int e0 = __builtin_amdgcn_readfirstlane(rowstart[n]);
    int e1 = __builtin_amdgcn_readfirstlane(rowstart[n + 1]);
    int e = e0;
    for (; e + 8 <= e1; e += 8) {
        int s0 = esrc[e],     s1 = esrc[e + 1], s2 = esrc[e + 2], s3 = esrc[e + 3];
        int s4 = esrc[e + 4], s5 = esrc[e + 5], s6 = esrc[e + 6], s7 = esrc[e + 7];
        float w0 = ew[e],     w1 = ew[e + 1], w2 = ew[e + 2], w3 = ew[e + 3];
        float w4 = ew[e + 4], w5 = ew[e + 5], w6 = ew[e + 6], w7 = ew[e + 7];
        float v0 = bf2f(hl[(size_t)s0 * 64]);
        float v1 = bf2f(hl[(size_t)s1 * 64]);
        float v2 = bf2f(hl[(size_t)s2 * 64]);
        float v3 = bf2f(hl[(size_t)s3 * 64]);
        float v4 = bf2f(hl[(size_t)s4 * 64]);
        float v5 = bf2f(hl[(size_t)s5 * 64]);
        float v6 = bf2f(hl[(size_t)s6 * 64]);
        float v7 = bf2f(hl[(size_t)s7 * 64]);
        acc = fmaf(w0, v0, acc); acc = fmaf(w1, v1, acc);
        acc = fmaf(w2, v2, acc); acc = fmaf(w3, v3, acc);
        acc = fmaf(w4, v4, acc); acc = fmaf(w5, v5, acc);
        acc = fmaf(w6, v6, acc); acc = fmaf(w7, v7, acc);
    }
    for (; e < e1; ++e)
        acc = fmaf(ew[e], bf2f(hl[(size_t)esrc[e] * 64]), acc);
    float dn = dinv[n];
    float r = fmaf(acc, dn, fmaf(bf2f(hl[(size_t)n * 64]), dn * dn, b2[lane]));
    float m = r;
#pragma unroll
    for (int off = 32; off; off >>= 1) m = fmaxf(m, __shfl_xor(m, off));
    float ex = __expf(r - m);
    float ssum = ex;
#pragma unroll
    for (int off = 32; off; off >>= 1) ssum += __shfl_xor(ssum, off);
    out[(size_t)n * 64 + lane] = r - m - __logf(ssum);
}

// ---------------- launch ----------------

extern "C" void kernel_launch(void* const* d_in, const int* in_sizes, int n_in,
                              void* d_out, int out_size, void* d_ws, size_t ws_size,
                              hipStream_t stream) {
    const float* x  = (const float*)d_in[0];
    const float* W1 = (const float*)d_in[1];
    const float* b1 = (const float*)d_in[2];
    const float* W2 = (const float*)d_in[3];
    const float* b2 = (const float*)d_in[4];
    const int*   ei = (const int*)d_in[5];
    int E = in_sizes[5] / 2;
    const int* src = ei;
    const int* dst = ei + E;
    float* out = (float*)d_out;

    int nblk = (E + EPB - 1) / EPB;   // 782

    char* wsp = (char*)d_ws;
    auto alloc = [&](size_t bytes) {
        char* p = wsp;
        wsp += (bytes + 255) & ~(size_t)255;
        return p;
    };
    int*    hist     = (int*)alloc((size_t)NBIN * nblk * 4);
    int*    offl     = (int*)alloc((size_t)NBIN * nblk * 4);
    int*    btot     = (int*)alloc((size_t)NBIN * 4);
    int*    binoff   = (int*)alloc((size_t)(NBIN + 1) * 4);
    int*    rowstart = (int*)alloc((size_t)(NODES + 1) * 4);
    float*  dinv     = (float*)alloc((size_t)NODES * 4);
    int2*   tmp      = (int2*)alloc((size_t)E * 8);
    int*    esrc     = (int*)alloc((size_t)E * 4);
    float*  ew       = (float*)alloc((size_t)E * 4);
    ushort* w1t      = (ushort*)alloc((size_t)256 * 512 * 2);
    ushort* w2t      = (ushort*)alloc((size_t)64 * 256 * 2);
    uchar*  h1f8     = (uchar*)alloc((size_t)NODES * 256);
    ushort* h1ab     = (ushort*)alloc((size_t)NODES * 256 * 2);
    ushort* h2b      = (ushort*)alloc((size_t)NODES * 64 * 2);

    // ---- CSR prefix (hist + scans) ----
    k_hist<<<nblk, 256, 0, stream>>>(dst, E, hist, nblk);
    k_scanbin<<<NBIN, 1024, 0, stream>>>(hist, offl, btot, nblk);
    k_scanoff<<<1, 256, 0, stream>>>(btot, binoff, rowstart, E);

    // ---- weight casts ----
    k_castT<<<(512 * 256 + 255) / 256, 256, 0, stream>>>(W1, w1t, 512, 256);
    k_castT<<<(256 * 64 + 255) / 256, 256, 0, stream>>>(W2, w2t, 256, 64);

    // ---- fused: GEMM1 ∥ edge partition ----
    int gemmBlocks = ((NODES + 63) / 64) * 2;   // 1564 (bm x 2 bn tiles)
    k_gemm1_part<<<gemmBlocks + nblk, 256, 0, stream>>>(
        x, w1t, h1f8, NODES, 512,
        src, dst, E, offl, binoff, nblk, tmp, gemmBlocks);

    // ---- CSR finalize ----
    k_csr<<<NBIN, 256, 0, stream>>>(tmp, binoff, rowstart, dinv, esrc);
    k_wfill<<<(E + 255) / 256, 256, 0, stream>>>(esrc, dinv, ew, E);

    // ---- layer 1 agg ----
    k_agg1<<<(NODES + 3) / 4, 256, 0, stream>>>(h1f8, rowstart, esrc, ew, dinv, b1, h1ab);

    // ---- layer 2 ----
    k_gemm2<<<(NODES + 63) / 64, 256, 0, stream>>>(h1ab, w2t, h2b, NODES, 256);
    k_agg2<<<(NODES + 3) / 4, 256, 0, stream>>>(h2b, rowstart, esrc, ew, dinv, b2, out);
}